// Round 3
// baseline (4257.556 us; speedup 1.0000x reference)
//
#include <hip/hip_runtime.h>
#include <math.h>

#define NN 100000
#define KEXP 4
#define EE 1600000
#define EPSV 1e-5f
#define NBLK 391        // ceil(100000/256)
#define BSHIFT 9
#define NBUCK 196       // ceil(100000/512)
#define ZCH 2           // chunks per bucket in bucket_scatter

// ---------------- degree histogram (all experts) ----------------
__global__ __launch_bounds__(256) void deg_kernel(const int* __restrict__ edge,
                                                  int* __restrict__ cnt, int n, int E) {
    int k = blockIdx.y;
    int e = blockIdx.x * 256 + threadIdx.x;
    if (e < E) {
        int d = edge[(size_t)k * 2 * E + E + e];
        atomicAdd(&cnt[(size_t)k * n + d], 1);
    }
}

__global__ __launch_bounds__(256) void dis_kernel(const int* __restrict__ cnt,
                                                  float* __restrict__ dis, int total) {
    int i = blockIdx.x * 256 + threadIdx.x;
    if (i < total) dis[i] = rsqrtf((float)cnt[i] + 2.0f);
}

// ---------------- CSR build: per-block inclusive scan ----------------
__global__ __launch_bounds__(256) void scan_blocks(const int* __restrict__ cnt,
                                                   int* __restrict__ rowptr,
                                                   int* __restrict__ bsum, int n) {
    int k = blockIdx.y;
    int t = threadIdx.x;
    int i = blockIdx.x * 256 + t;
    __shared__ int sd[256];
    int v = (i < n) ? cnt[(size_t)k * n + i] : 0;
    sd[t] = v;
    __syncthreads();
    for (int o = 1; o < 256; o <<= 1) {
        int x = (t >= o) ? sd[t - o] : 0;
        __syncthreads();
        sd[t] += x;
        __syncthreads();
    }
    if (i < n) rowptr[(size_t)k * (n + 1) + i] = sd[t] - v;  // exclusive-within-block
    if (t == 255) bsum[k * gridDim.x + blockIdx.x] = sd[255];
}

__global__ __launch_bounds__(512) void scan_bsum(int* __restrict__ bsum,
                                                 int* __restrict__ rowptr,
                                                 int nblk, int n, int E) {
    int k = blockIdx.x;
    int t = threadIdx.x;
    __shared__ int sd[512];
    int v = (t < nblk) ? bsum[k * nblk + t] : 0;
    sd[t] = v;
    __syncthreads();
    for (int o = 1; o < 512; o <<= 1) {
        int x = (t >= o) ? sd[t - o] : 0;
        __syncthreads();
        sd[t] += x;
        __syncthreads();
    }
    if (t < nblk) bsum[k * nblk + t] = sd[t] - v;  // exclusive block offsets
    if (t == 0) rowptr[(size_t)k * (n + 1) + n] = E;
}

__global__ __launch_bounds__(256) void scan_add(int* __restrict__ rowptr,
                                                const int* __restrict__ bsum,
                                                int* __restrict__ cursor, int n) {
    int k = blockIdx.y;
    int i = blockIdx.x * 256 + threadIdx.x;
    if (i < n) {
        int off = bsum[k * gridDim.x + blockIdx.x];
        size_t idx = (size_t)k * (n + 1) + i;
        int val = rowptr[idx] + off;
        rowptr[idx] = val;
        cursor[(size_t)k * n + i] = val;
    }
}

// ---------------- bucketed two-pass sort (replaces direct scatter) --------
__global__ __launch_bounds__(256) void binit_kernel(const int* __restrict__ rowptr,
                                                    int* __restrict__ bcur, int n) {
    int i = blockIdx.x * 256 + threadIdx.x;  // over K*NBUCK
    if (i >= KEXP * NBUCK) return;
    int k = i / NBUCK, b = i % NBUCK;
    int node = b << BSHIFT;
    if (node > n) node = n;
    bcur[i] = rowptr[(size_t)k * (n + 1) + node];
}

__global__ __launch_bounds__(256) void partition_kernel(const int* __restrict__ edge,
                                                        int* __restrict__ bcur,
                                                        unsigned long long* __restrict__ bstream,
                                                        int n, int E) {
    int k = blockIdx.y;
    int e = blockIdx.x * 256 + threadIdx.x;
    if (e >= E) return;
    const int* base = edge + (size_t)k * 2 * E;
    int s = base[e];
    int d = base[E + e];
    int b = d >> BSHIFT;
    int pos = atomicAdd(&bcur[k * NBUCK + b], 1);
    bstream[(size_t)k * E + pos] = ((unsigned long long)(unsigned)d << 32) | (unsigned)s;
}

__global__ __launch_bounds__(256) void bucket_scatter(const int* __restrict__ rowptr,
                                                      const unsigned long long* __restrict__ bstream,
                                                      int* __restrict__ cursor,
                                                      int* __restrict__ adj, int n, int E) {
    int k = blockIdx.y;
    int b = blockIdx.x;
    int z = blockIdx.z;
    int nb = b << BSHIFT;
    if (nb >= n) return;
    int ne = nb + (1 << BSHIFT);
    if (ne > n) ne = n;
    const int* rp = rowptr + (size_t)k * (n + 1);
    int beg = rp[nb], end = rp[ne];
    const unsigned long long* bs = bstream + (size_t)k * E;
    int* cur = cursor + (size_t)k * n;
    int* aj = adj + (size_t)k * E;
    for (int p = beg + z * 256 + (int)threadIdx.x; p < end; p += ZCH * 256) {
        unsigned long long pk = bs[p];
        int s = (int)(pk & 0xffffffffull);
        int d = (int)(pk >> 32);
        int pos = atomicAdd(&cur[d], 1);
        aj[pos] = s;
    }
}

// ---------------- GEMM1: h = A @ W (M x 256 x 64) ----------------
__global__ __launch_bounds__(256) void gemm1_kernel(
    const float* __restrict__ A,    // [M,256]
    const float* __restrict__ W,    // [256,64]
    float* __restrict__ h,          // [M,64]
    int M) {
    __shared__ __align__(16) float As[64][65];
    __shared__ __align__(16) float Ws[64][68];
    int t = threadIdx.x;
    int row0 = blockIdx.x * 64;
    int tr = t >> 4;   // 0..15
    int tc = t & 15;   // 0..15
    float acc[4][4] = {{0.f}};

    for (int kc = 0; kc < 256; kc += 64) {
        for (int i = 0; i < 4; i++) {
            int fid = t + i * 256;
            int r = fid >> 4;
            int c4 = (fid & 15) << 2;
            int row = row0 + r;
            float4 v = make_float4(0.f, 0.f, 0.f, 0.f);
            if (row < M) v = *(const float4*)&A[(size_t)row * 256 + kc + c4];
            As[r][c4] = v.x; As[r][c4 + 1] = v.y; As[r][c4 + 2] = v.z; As[r][c4 + 3] = v.w;
        }
        for (int i = 0; i < 4; i++) {
            int fid = t + i * 256;
            int r = fid >> 4;
            int c4 = (fid & 15) << 2;
            float4 v = *(const float4*)&W[(size_t)(kc + r) * 64 + c4];
            *(float4*)&Ws[r][c4] = v;
        }
        __syncthreads();
        for (int kk = 0; kk < 64; kk++) {
            float a0 = As[tr * 4 + 0][kk];
            float a1 = As[tr * 4 + 1][kk];
            float a2 = As[tr * 4 + 2][kk];
            float a3 = As[tr * 4 + 3][kk];
            float4 w = *(const float4*)&Ws[kk][tc * 4];
            acc[0][0] += a0 * w.x; acc[0][1] += a0 * w.y; acc[0][2] += a0 * w.z; acc[0][3] += a0 * w.w;
            acc[1][0] += a1 * w.x; acc[1][1] += a1 * w.y; acc[1][2] += a1 * w.z; acc[1][3] += a1 * w.w;
            acc[2][0] += a2 * w.x; acc[2][1] += a2 * w.y; acc[2][2] += a2 * w.z; acc[2][3] += a2 * w.w;
            acc[3][0] += a3 * w.x; acc[3][1] += a3 * w.y; acc[3][2] += a3 * w.z; acc[3][3] += a3 * w.w;
        }
        __syncthreads();
    }
    for (int i = 0; i < 4; i++) {
        int row = row0 + tr * 4 + i;
        if (row >= M) continue;
        float4 v = make_float4(acc[i][0], acc[i][1], acc[i][2], acc[i][3]);
        *(float4*)&h[(size_t)row * 64 + tc * 4] = v;
    }
}

// ---------------- gather agg1: wave per node, lane = feature; fused relu ----
__global__ __launch_bounds__(256) void gather1(const int* __restrict__ rowptr,
                                               const int* __restrict__ adj,
                                               const float* __restrict__ dis,
                                               const float* __restrict__ h,
                                               const float* __restrict__ b1,
                                               float* __restrict__ x, int n) {
    int node = blockIdx.x * 4 + (threadIdx.x >> 6);
    int lane = threadIdx.x & 63;
    if (node >= n) return;
    int beg = rowptr[node], end = rowptr[node + 1];
    float acc = 0.f;
    int j = beg;
    for (; j + 2 <= end; j += 2) {
        int s0 = adj[j], s1 = adj[j + 1];
        float d0 = dis[s0], d1 = dis[s1];
        float v0 = h[(size_t)s0 * 64 + lane];
        float v1 = h[(size_t)s1 * 64 + lane];
        acc += d0 * v0;
        acc += d1 * v1;
    }
    if (j < end) {
        int s0 = adj[j];
        acc += dis[s0] * h[(size_t)s0 * 64 + lane];
    }
    float dn = dis[node];
    float val = dn * acc + 2.f * dn * dn * h[(size_t)node * 64 + lane] + b1[lane];
    x[(size_t)node * 64 + lane] = fmaxf(val, 0.f);
}

// ---------------- BN column stats: grid-stride + atomic finalize ----------
__global__ __launch_bounds__(256) void stats_kernel(const float* __restrict__ x,
                                                    float* __restrict__ accum, int n) {
    int c = threadIdx.x & 63;
    int w = threadIdx.x >> 6;
    float s = 0.f, q = 0.f;
    for (int r = blockIdx.x * 4 + w; r < n; r += gridDim.x * 4) {
        float v = x[(size_t)r * 64 + c];
        s += v; q += v * v;
    }
    __shared__ float ls[4][64];
    __shared__ float lq[4][64];
    ls[w][c] = s; lq[w][c] = q;
    __syncthreads();
    if (threadIdx.x < 64) {
        float S = ls[0][c] + ls[1][c] + ls[2][c] + ls[3][c];
        float Q = lq[0][c] + lq[1][c] + lq[2][c] + lq[3][c];
        unsafeAtomicAdd(&accum[c], S);
        unsafeAtomicAdd(&accum[64 + c], Q);
    }
}

__global__ void stats_fin(const float* __restrict__ accum,
                          float* __restrict__ mu_istd, int M) {
    int c = threadIdx.x;  // 64 threads
    float mu = accum[c] / (float)M;
    float var = accum[64 + c] / (float)M - mu * mu;
    mu_istd[c] = mu;
    mu_istd[64 + c] = rsqrtf(var + EPSV);
}

// ---------------- BN apply + GEMM2 (64 -> 2) ----------------
__global__ __launch_bounds__(256) void bn_gemm2(const float* __restrict__ x,
                                                const float* __restrict__ mu_istd,
                                                const float* __restrict__ g,
                                                const float* __restrict__ bt,
                                                const float* __restrict__ W2,
                                                float* __restrict__ h2, int M) {
    int wid = (int)((blockIdx.x * (size_t)blockDim.x + threadIdx.x) >> 6);
    int c = threadIdx.x & 63;
    if (wid >= M) return;
    float v = x[(size_t)wid * 64 + c];
    v = (v - mu_istd[c]) * mu_istd[64 + c] * g[c] + bt[c];
    float p0 = v * W2[c * 2];
    float p1 = v * W2[c * 2 + 1];
    for (int off = 32; off; off >>= 1) {
        p0 += __shfl_down(p0, off);
        p1 += __shfl_down(p1, off);
    }
    if (c == 0) {
        float2 o = make_float2(p0, p1);
        *(float2*)&h2[(size_t)wid * 2] = o;
    }
}

// ---------------- gather agg2: thread per node ----------------
__global__ __launch_bounds__(256) void gather2(const int* __restrict__ rowptr,
                                               const int* __restrict__ adj,
                                               const float* __restrict__ dis,
                                               const float* __restrict__ h2,
                                               const float* __restrict__ b2,
                                               float* __restrict__ agg2, int n) {
    int node = blockIdx.x * 256 + threadIdx.x;
    if (node >= n) return;
    int beg = rowptr[node], end = rowptr[node + 1];
    float a0 = 0.f, a1 = 0.f;
    int j = beg;
    for (; j + 2 <= end; j += 2) {
        int s0 = adj[j], s1 = adj[j + 1];
        float d0 = dis[s0], d1 = dis[s1];
        float2 v0 = *(const float2*)&h2[(size_t)s0 * 2];
        float2 v1 = *(const float2*)&h2[(size_t)s1 * 2];
        a0 += d0 * v0.x + d1 * v1.x;
        a1 += d0 * v0.y + d1 * v1.y;
    }
    if (j < end) {
        int s0 = adj[j];
        float d0 = dis[s0];
        float2 v0 = *(const float2*)&h2[(size_t)s0 * 2];
        a0 += d0 * v0.x;
        a1 += d0 * v0.y;
    }
    float dn = dis[node];
    float sc = 2.f * dn * dn;
    float2 hv = *(const float2*)&h2[(size_t)node * 2];
    float2 o;
    o.x = dn * a0 + sc * hv.x + b2[0];
    o.y = dn * a1 + sc * hv.y + b2[1];
    *(float2*)&agg2[(size_t)node * 2] = o;
}

// ---------------- gating + mixture output ----------------
__global__ __launch_bounds__(256) void final_kernel(const float* __restrict__ moe,
                                                    const float* __restrict__ Wg,
                                                    const float* __restrict__ bg,
                                                    const float* __restrict__ agg2,  // [K][N][2]
                                                    float* __restrict__ out, int M) {
    int n = (int)((blockIdx.x * (size_t)blockDim.x + threadIdx.x) >> 6);
    int lane = threadIdx.x & 63;
    if (n >= M) return;
    float4 mf = *(const float4*)&moe[(size_t)n * 256 + lane * 4];
    const float* wr = &Wg[lane * 16];
    float a0 = mf.x * wr[0] + mf.y * wr[4] + mf.z * wr[8] + mf.w * wr[12];
    float a1 = mf.x * wr[1] + mf.y * wr[5] + mf.z * wr[9] + mf.w * wr[13];
    float a2 = mf.x * wr[2] + mf.y * wr[6] + mf.z * wr[10] + mf.w * wr[14];
    float a3 = mf.x * wr[3] + mf.y * wr[7] + mf.z * wr[11] + mf.w * wr[15];
    for (int mask = 1; mask < 64; mask <<= 1) {
        a0 += __shfl_xor(a0, mask);
        a1 += __shfl_xor(a1, mask);
        a2 += __shfl_xor(a2, mask);
        a3 += __shfl_xor(a3, mask);
    }
    if (lane == 0) {
        float gl[4] = {a0 + bg[0], a1 + bg[1], a2 + bg[2], a3 + bg[3]};
        float m = fmaxf(fmaxf(gl[0], gl[1]), fmaxf(gl[2], gl[3]));
        float w[4];
        float wsum = 0.f;
        for (int kk = 0; kk < 4; kk++) { w[kk] = expf(gl[kk] - m); wsum += w[kk]; }
        float o0 = 0.f, o1 = 0.f, q0 = 0.f, q1 = 0.f;
        for (int kk = 0; kk < 4; kk++) {
            float l0 = agg2[((size_t)kk * M + n) * 2];
            float l1 = agg2[((size_t)kk * M + n) * 2 + 1];
            float mm = fmaxf(l0, l1);
            float lse = mm + logf(expf(l0 - mm) + expf(l1 - mm));
            float lp0 = l0 - lse, lp1 = l1 - lse;
            float wk = w[kk] / wsum;
            o0 += wk * lp0; o1 += wk * lp1;
            q0 += wk * expf(lp0); q1 += wk * expf(lp1);
        }
        out[(size_t)n * 2] = o0;
        out[(size_t)n * 2 + 1] = o1;
        out[(size_t)2 * M + n * 2] = q0;
        out[(size_t)2 * M + n * 2 + 1] = q1;
    }
}

extern "C" void kernel_launch(void* const* d_in, const int* in_sizes, int n_in,
                              void* d_out, int out_size, void* d_ws, size_t ws_size,
                              hipStream_t stream) {
    const float* flatten = (const float*)d_in[0];
    const float* moe     = (const float*)d_in[1];
    const int*   edge    = (const int*)d_in[2];   // [K][2][E]
    const float* W1      = (const float*)d_in[3]; // [K][256][64]
    const float* b1      = (const float*)d_in[4]; // [K][64]
    const float* gamma   = (const float*)d_in[5];
    const float* beta    = (const float*)d_in[6];
    const float* W2      = (const float*)d_in[7]; // [K][64][2]
    const float* b2      = (const float*)d_in[8]; // [K][2]
    const float* Wg      = (const float*)d_in[9]; // [256][4]
    const float* bg      = (const float*)d_in[10];
    float* out = (float*)d_out;

    const int N = NN, E = EE, K = KEXP;

    char* ws = (char*)d_ws;
    size_t off = 0;
    auto alloc = [&](size_t bytes) -> void* {
        void* p = (void*)(ws + off);
        off += (bytes + 255) & ~(size_t)255;
        return p;
    };
    int*   cnt     = (int*)alloc((size_t)K * N * 4);
    int*   rowptr  = (int*)alloc((size_t)K * (N + 1) * 4);
    int*   cursor  = (int*)alloc((size_t)K * N * 4);
    float* dis     = (float*)alloc((size_t)K * N * 4);
    int*   bsum    = (int*)alloc((size_t)K * NBLK * 4);
    int*   bcur    = (int*)alloc((size_t)K * NBUCK * 4);
    int*   adj     = (int*)alloc((size_t)K * E * 4);
    float* h       = (float*)alloc((size_t)N * 64 * 4);
    float* x       = (float*)alloc((size_t)N * 64 * 4);
    float* h2      = (float*)alloc((size_t)N * 2 * 4);
    float* agg2    = (float*)alloc((size_t)K * N * 2 * 4);
    float* accum   = (float*)alloc((size_t)K * 128 * 4);
    float* mu_istd = (float*)alloc(128 * 4);
    (void)ws_size; (void)in_sizes; (void)n_in; (void)out_size;

    // bstream (K*E*8 = 51.2 MB) aliases h+x (2 * 25.6 MB, contiguous):
    // only used before gemm1 writes h.
    unsigned long long* bstream = (unsigned long long*)h;

    const int egrid = (E + 255) / 256;

    // ---- batched CSR build for all experts (bucketed two-pass sort) ----
    hipMemsetAsync(cnt, 0, (size_t)K * N * 4, stream);
    hipMemsetAsync(accum, 0, (size_t)K * 128 * 4, stream);
    deg_kernel<<<dim3(egrid, K), 256, 0, stream>>>(edge, cnt, N, E);
    dis_kernel<<<(K * N + 255) / 256, 256, 0, stream>>>(cnt, dis, K * N);
    scan_blocks<<<dim3(NBLK, K), 256, 0, stream>>>(cnt, rowptr, bsum, N);
    scan_bsum<<<K, 512, 0, stream>>>(bsum, rowptr, NBLK, N, E);
    scan_add<<<dim3(NBLK, K), 256, 0, stream>>>(rowptr, bsum, cursor, N);
    binit_kernel<<<(K * NBUCK + 255) / 256, 256, 0, stream>>>(rowptr, bcur, N);
    partition_kernel<<<dim3(egrid, K), 256, 0, stream>>>(edge, bcur, bstream, N, E);
    bucket_scatter<<<dim3(NBUCK, K, ZCH), 256, 0, stream>>>(rowptr, bstream, cursor, adj, N, E);

    // ---- per-expert pipeline ----
    for (int k = 0; k < K; k++) {
        const int* rp = rowptr + (size_t)k * (N + 1);
        const int* aj = adj + (size_t)k * E;
        const float* dk = dis + (size_t)k * N;
        gemm1_kernel<<<(N + 63) / 64, 256, 0, stream>>>(
            flatten, W1 + (size_t)k * 256 * 64, h, N);
        gather1<<<(N + 3) / 4, 256, 0, stream>>>(
            rp, aj, dk, h, b1 + (size_t)k * 64, x, N);
        stats_kernel<<<400, 256, 0, stream>>>(x, accum + (size_t)k * 128, N);
        stats_fin<<<1, 64, 0, stream>>>(accum + (size_t)k * 128, mu_istd, N);
        bn_gemm2<<<(int)(((size_t)N * 64 + 255) / 256), 256, 0, stream>>>(
            x, mu_istd, gamma + (size_t)k * 64, beta + (size_t)k * 64,
            W2 + (size_t)k * 128, h2, N);
        gather2<<<(N + 255) / 256, 256, 0, stream>>>(
            rp, aj, dk, h2, b2 + (size_t)k * 2, agg2 + (size_t)k * N * 2, N);
    }
    final_kernel<<<(int)(((size_t)N * 64 + 255) / 256), 256, 0, stream>>>(
        moe, Wg, bg, agg2, out, N);
}

// Round 4
// 1653.585 us; speedup vs baseline: 2.5747x; 2.5747x over previous
//
#include <hip/hip_runtime.h>
#include <math.h>

#define NN 100000
#define KEXP 4
#define EE 1600000
#define EPSV 1e-5f
#define NBLK 391        // ceil(100000/256)
#define BSHIFT 9
#define NBUCK 196       // ceil(100000/512)
#define ZCH 2           // chunks per bucket in bucket_scatter
#define PCHUNK 16384    // edges per block in partition_kernel

// ---------------- degree histogram (all experts) ----------------
__global__ __launch_bounds__(256) void deg_kernel(const int* __restrict__ edge,
                                                  int* __restrict__ cnt, int n, int E) {
    int k = blockIdx.y;
    int e = blockIdx.x * 256 + threadIdx.x;
    if (e < E) {
        int d = edge[(size_t)k * 2 * E + E + e];
        atomicAdd(&cnt[(size_t)k * n + d], 1);
    }
}

__global__ __launch_bounds__(256) void dis_kernel(const int* __restrict__ cnt,
                                                  float* __restrict__ dis, int total) {
    int i = blockIdx.x * 256 + threadIdx.x;
    if (i < total) dis[i] = rsqrtf((float)cnt[i] + 2.0f);
}

// ---------------- CSR build: per-block inclusive scan ----------------
__global__ __launch_bounds__(256) void scan_blocks(const int* __restrict__ cnt,
                                                   int* __restrict__ rowptr,
                                                   int* __restrict__ bsum, int n) {
    int k = blockIdx.y;
    int t = threadIdx.x;
    int i = blockIdx.x * 256 + t;
    __shared__ int sd[256];
    int v = (i < n) ? cnt[(size_t)k * n + i] : 0;
    sd[t] = v;
    __syncthreads();
    for (int o = 1; o < 256; o <<= 1) {
        int x = (t >= o) ? sd[t - o] : 0;
        __syncthreads();
        sd[t] += x;
        __syncthreads();
    }
    if (i < n) rowptr[(size_t)k * (n + 1) + i] = sd[t] - v;  // exclusive-within-block
    if (t == 255) bsum[k * gridDim.x + blockIdx.x] = sd[255];
}

__global__ __launch_bounds__(512) void scan_bsum(int* __restrict__ bsum,
                                                 int* __restrict__ rowptr,
                                                 int nblk, int n, int E) {
    int k = blockIdx.x;
    int t = threadIdx.x;
    __shared__ int sd[512];
    int v = (t < nblk) ? bsum[k * nblk + t] : 0;
    sd[t] = v;
    __syncthreads();
    for (int o = 1; o < 512; o <<= 1) {
        int x = (t >= o) ? sd[t - o] : 0;
        __syncthreads();
        sd[t] += x;
        __syncthreads();
    }
    if (t < nblk) bsum[k * nblk + t] = sd[t] - v;  // exclusive block offsets
    if (t == 0) rowptr[(size_t)k * (n + 1) + n] = E;
}

__global__ __launch_bounds__(256) void scan_add(int* __restrict__ rowptr,
                                                const int* __restrict__ bsum,
                                                int* __restrict__ cursor, int n) {
    int k = blockIdx.y;
    int i = blockIdx.x * 256 + threadIdx.x;
    if (i < n) {
        int off = bsum[k * gridDim.x + blockIdx.x];
        size_t idx = (size_t)k * (n + 1) + i;
        int val = rowptr[idx] + off;
        rowptr[idx] = val;
        cursor[(size_t)k * n + i] = val;
    }
}

// ---------------- bucketed two-pass sort ----------------
__global__ __launch_bounds__(256) void binit_kernel(const int* __restrict__ rowptr,
                                                    int* __restrict__ bcur, int n) {
    int i = blockIdx.x * 256 + threadIdx.x;  // over K*NBUCK
    if (i >= KEXP * NBUCK) return;
    int k = i / NBUCK, b = i % NBUCK;
    int node = b << BSHIFT;
    if (node > n) node = n;
    bcur[i] = rowptr[(size_t)k * (n + 1) + node];
}

// LDS multi-split: per-block histogram -> one global atomic per bin per
// block -> rank-and-write. Kills the R3 contention (1.6M atomics on 196
// counters -> 77k atomics, ~98 per counter).
__global__ __launch_bounds__(256) void partition_kernel(const int* __restrict__ edge,
                                                        int* __restrict__ bcur,
                                                        unsigned long long* __restrict__ bstream,
                                                        int n, int E) {
    int k = blockIdx.y;
    int cbase = blockIdx.x * PCHUNK;
    const int* sp = edge + (size_t)k * 2 * E;
    const int* dp = sp + E;
    __shared__ int hist[NBUCK];
    __shared__ int base[NBUCK];
    for (int i = threadIdx.x; i < NBUCK; i += 256) hist[i] = 0;
    __syncthreads();
    int cend = cbase + PCHUNK;
    if (cend > E) cend = E;
    for (int e = cbase + (int)threadIdx.x; e < cend; e += 256) {
        atomicAdd(&hist[dp[e] >> BSHIFT], 1);
    }
    __syncthreads();
    for (int i = threadIdx.x; i < NBUCK; i += 256) {
        int c = hist[i];
        base[i] = c ? atomicAdd(&bcur[k * NBUCK + i], c) : 0;
        hist[i] = 0;
    }
    __syncthreads();
    unsigned long long* bs = bstream + (size_t)k * E;
    for (int e = cbase + (int)threadIdx.x; e < cend; e += 256) {
        int s = sp[e];
        int d = dp[e];
        int b = d >> BSHIFT;
        int r = atomicAdd(&hist[b], 1);
        bs[base[b] + r] = ((unsigned long long)(unsigned)d << 32) | (unsigned)s;
    }
}

__global__ __launch_bounds__(256) void bucket_scatter(const int* __restrict__ rowptr,
                                                      const unsigned long long* __restrict__ bstream,
                                                      int* __restrict__ cursor,
                                                      int* __restrict__ adj, int n, int E) {
    int k = blockIdx.y;
    int b = blockIdx.x;
    int z = blockIdx.z;
    int nb = b << BSHIFT;
    if (nb >= n) return;
    int ne = nb + (1 << BSHIFT);
    if (ne > n) ne = n;
    const int* rp = rowptr + (size_t)k * (n + 1);
    int beg = rp[nb], end = rp[ne];
    const unsigned long long* bs = bstream + (size_t)k * E;
    int* cur = cursor + (size_t)k * n;
    int* aj = adj + (size_t)k * E;
    for (int p = beg + z * 256 + (int)threadIdx.x; p < end; p += ZCH * 256) {
        unsigned long long pk = bs[p];
        int s = (int)(pk & 0xffffffffull);
        int d = (int)(pk >> 32);
        int pos = atomicAdd(&cur[d], 1);
        aj[pos] = s;
    }
}

// ---------------- GEMM1: h = A @ W (M x 256 x 64) ----------------
__global__ __launch_bounds__(256) void gemm1_kernel(
    const float* __restrict__ A,    // [M,256]
    const float* __restrict__ W,    // [256,64]
    float* __restrict__ h,          // [M,64]
    int M) {
    __shared__ __align__(16) float As[64][65];
    __shared__ __align__(16) float Ws[64][68];
    int t = threadIdx.x;
    int row0 = blockIdx.x * 64;
    int tr = t >> 4;   // 0..15
    int tc = t & 15;   // 0..15
    float acc[4][4] = {{0.f}};

    for (int kc = 0; kc < 256; kc += 64) {
        for (int i = 0; i < 4; i++) {
            int fid = t + i * 256;
            int r = fid >> 4;
            int c4 = (fid & 15) << 2;
            int row = row0 + r;
            float4 v = make_float4(0.f, 0.f, 0.f, 0.f);
            if (row < M) v = *(const float4*)&A[(size_t)row * 256 + kc + c4];
            As[r][c4] = v.x; As[r][c4 + 1] = v.y; As[r][c4 + 2] = v.z; As[r][c4 + 3] = v.w;
        }
        for (int i = 0; i < 4; i++) {
            int fid = t + i * 256;
            int r = fid >> 4;
            int c4 = (fid & 15) << 2;
            float4 v = *(const float4*)&W[(size_t)(kc + r) * 64 + c4];
            *(float4*)&Ws[r][c4] = v;
        }
        __syncthreads();
        for (int kk = 0; kk < 64; kk++) {
            float a0 = As[tr * 4 + 0][kk];
            float a1 = As[tr * 4 + 1][kk];
            float a2 = As[tr * 4 + 2][kk];
            float a3 = As[tr * 4 + 3][kk];
            float4 w = *(const float4*)&Ws[kk][tc * 4];
            acc[0][0] += a0 * w.x; acc[0][1] += a0 * w.y; acc[0][2] += a0 * w.z; acc[0][3] += a0 * w.w;
            acc[1][0] += a1 * w.x; acc[1][1] += a1 * w.y; acc[1][2] += a1 * w.z; acc[1][3] += a1 * w.w;
            acc[2][0] += a2 * w.x; acc[2][1] += a2 * w.y; acc[2][2] += a2 * w.z; acc[2][3] += a2 * w.w;
            acc[3][0] += a3 * w.x; acc[3][1] += a3 * w.y; acc[3][2] += a3 * w.z; acc[3][3] += a3 * w.w;
        }
        __syncthreads();
    }
    for (int i = 0; i < 4; i++) {
        int row = row0 + tr * 4 + i;
        if (row >= M) continue;
        float4 v = make_float4(acc[i][0], acc[i][1], acc[i][2], acc[i][3]);
        *(float4*)&h[(size_t)row * 64 + tc * 4] = v;
    }
}

// ---------------- gather agg1: wave per node, lane = feature; fused relu ----
__global__ __launch_bounds__(256) void gather1(const int* __restrict__ rowptr,
                                               const int* __restrict__ adj,
                                               const float* __restrict__ dis,
                                               const float* __restrict__ h,
                                               const float* __restrict__ b1,
                                               float* __restrict__ x, int n) {
    int node = blockIdx.x * 4 + (threadIdx.x >> 6);
    int lane = threadIdx.x & 63;
    if (node >= n) return;
    int beg = rowptr[node], end = rowptr[node + 1];
    float acc = 0.f;
    int j = beg;
    for (; j + 2 <= end; j += 2) {
        int s0 = adj[j], s1 = adj[j + 1];
        float d0 = dis[s0], d1 = dis[s1];
        float v0 = h[(size_t)s0 * 64 + lane];
        float v1 = h[(size_t)s1 * 64 + lane];
        acc += d0 * v0;
        acc += d1 * v1;
    }
    if (j < end) {
        int s0 = adj[j];
        acc += dis[s0] * h[(size_t)s0 * 64 + lane];
    }
    float dn = dis[node];
    float val = dn * acc + 2.f * dn * dn * h[(size_t)node * 64 + lane] + b1[lane];
    x[(size_t)node * 64 + lane] = fmaxf(val, 0.f);
}

// ---------------- BN column stats: grid-stride + atomic finalize ----------
__global__ __launch_bounds__(256) void stats_kernel(const float* __restrict__ x,
                                                    float* __restrict__ accum, int n) {
    int c = threadIdx.x & 63;
    int w = threadIdx.x >> 6;
    float s = 0.f, q = 0.f;
    for (int r = blockIdx.x * 4 + w; r < n; r += gridDim.x * 4) {
        float v = x[(size_t)r * 64 + c];
        s += v; q += v * v;
    }
    __shared__ float ls[4][64];
    __shared__ float lq[4][64];
    ls[w][c] = s; lq[w][c] = q;
    __syncthreads();
    if (threadIdx.x < 64) {
        float S = ls[0][c] + ls[1][c] + ls[2][c] + ls[3][c];
        float Q = lq[0][c] + lq[1][c] + lq[2][c] + lq[3][c];
        unsafeAtomicAdd(&accum[c], S);
        unsafeAtomicAdd(&accum[64 + c], Q);
    }
}

__global__ void stats_fin(const float* __restrict__ accum,
                          float* __restrict__ mu_istd, int M) {
    int c = threadIdx.x;  // 64 threads
    float mu = accum[c] / (float)M;
    float var = accum[64 + c] / (float)M - mu * mu;
    mu_istd[c] = mu;
    mu_istd[64 + c] = rsqrtf(var + EPSV);
}

// ---------------- BN apply + GEMM2 (64 -> 2) ----------------
__global__ __launch_bounds__(256) void bn_gemm2(const float* __restrict__ x,
                                                const float* __restrict__ mu_istd,
                                                const float* __restrict__ g,
                                                const float* __restrict__ bt,
                                                const float* __restrict__ W2,
                                                float* __restrict__ h2, int M) {
    int wid = (int)((blockIdx.x * (size_t)blockDim.x + threadIdx.x) >> 6);
    int c = threadIdx.x & 63;
    if (wid >= M) return;
    float v = x[(size_t)wid * 64 + c];
    v = (v - mu_istd[c]) * mu_istd[64 + c] * g[c] + bt[c];
    float p0 = v * W2[c * 2];
    float p1 = v * W2[c * 2 + 1];
    for (int off = 32; off; off >>= 1) {
        p0 += __shfl_down(p0, off);
        p1 += __shfl_down(p1, off);
    }
    if (c == 0) {
        float2 o = make_float2(p0, p1);
        *(float2*)&h2[(size_t)wid * 2] = o;
    }
}

// ---------------- gather agg2: thread per node ----------------
__global__ __launch_bounds__(256) void gather2(const int* __restrict__ rowptr,
                                               const int* __restrict__ adj,
                                               const float* __restrict__ dis,
                                               const float* __restrict__ h2,
                                               const float* __restrict__ b2,
                                               float* __restrict__ agg2, int n) {
    int node = blockIdx.x * 256 + threadIdx.x;
    if (node >= n) return;
    int beg = rowptr[node], end = rowptr[node + 1];
    float a0 = 0.f, a1 = 0.f;
    int j = beg;
    for (; j + 2 <= end; j += 2) {
        int s0 = adj[j], s1 = adj[j + 1];
        float d0 = dis[s0], d1 = dis[s1];
        float2 v0 = *(const float2*)&h2[(size_t)s0 * 2];
        float2 v1 = *(const float2*)&h2[(size_t)s1 * 2];
        a0 += d0 * v0.x + d1 * v1.x;
        a1 += d0 * v0.y + d1 * v1.y;
    }
    if (j < end) {
        int s0 = adj[j];
        float d0 = dis[s0];
        float2 v0 = *(const float2*)&h2[(size_t)s0 * 2];
        a0 += d0 * v0.x;
        a1 += d0 * v0.y;
    }
    float dn = dis[node];
    float sc = 2.f * dn * dn;
    float2 hv = *(const float2*)&h2[(size_t)node * 2];
    float2 o;
    o.x = dn * a0 + sc * hv.x + b2[0];
    o.y = dn * a1 + sc * hv.y + b2[1];
    *(float2*)&agg2[(size_t)node * 2] = o;
}

// ---------------- gating + mixture output ----------------
__global__ __launch_bounds__(256) void final_kernel(const float* __restrict__ moe,
                                                    const float* __restrict__ Wg,
                                                    const float* __restrict__ bg,
                                                    const float* __restrict__ agg2,  // [K][N][2]
                                                    float* __restrict__ out, int M) {
    int n = (int)((blockIdx.x * (size_t)blockDim.x + threadIdx.x) >> 6);
    int lane = threadIdx.x & 63;
    if (n >= M) return;
    float4 mf = *(const float4*)&moe[(size_t)n * 256 + lane * 4];
    const float* wr = &Wg[lane * 16];
    float a0 = mf.x * wr[0] + mf.y * wr[4] + mf.z * wr[8] + mf.w * wr[12];
    float a1 = mf.x * wr[1] + mf.y * wr[5] + mf.z * wr[9] + mf.w * wr[13];
    float a2 = mf.x * wr[2] + mf.y * wr[6] + mf.z * wr[10] + mf.w * wr[14];
    float a3 = mf.x * wr[3] + mf.y * wr[7] + mf.z * wr[11] + mf.w * wr[15];
    for (int mask = 1; mask < 64; mask <<= 1) {
        a0 += __shfl_xor(a0, mask);
        a1 += __shfl_xor(a1, mask);
        a2 += __shfl_xor(a2, mask);
        a3 += __shfl_xor(a3, mask);
    }
    if (lane == 0) {
        float gl[4] = {a0 + bg[0], a1 + bg[1], a2 + bg[2], a3 + bg[3]};
        float m = fmaxf(fmaxf(gl[0], gl[1]), fmaxf(gl[2], gl[3]));
        float w[4];
        float wsum = 0.f;
        for (int kk = 0; kk < 4; kk++) { w[kk] = expf(gl[kk] - m); wsum += w[kk]; }
        float o0 = 0.f, o1 = 0.f, q0 = 0.f, q1 = 0.f;
        for (int kk = 0; kk < 4; kk++) {
            float l0 = agg2[((size_t)kk * M + n) * 2];
            float l1 = agg2[((size_t)kk * M + n) * 2 + 1];
            float mm = fmaxf(l0, l1);
            float lse = mm + logf(expf(l0 - mm) + expf(l1 - mm));
            float lp0 = l0 - lse, lp1 = l1 - lse;
            float wk = w[kk] / wsum;
            o0 += wk * lp0; o1 += wk * lp1;
            q0 += wk * expf(lp0); q1 += wk * expf(lp1);
        }
        out[(size_t)n * 2] = o0;
        out[(size_t)n * 2 + 1] = o1;
        out[(size_t)2 * M + n * 2] = q0;
        out[(size_t)2 * M + n * 2 + 1] = q1;
    }
}

extern "C" void kernel_launch(void* const* d_in, const int* in_sizes, int n_in,
                              void* d_out, int out_size, void* d_ws, size_t ws_size,
                              hipStream_t stream) {
    const float* flatten = (const float*)d_in[0];
    const float* moe     = (const float*)d_in[1];
    const int*   edge    = (const int*)d_in[2];   // [K][2][E]
    const float* W1      = (const float*)d_in[3]; // [K][256][64]
    const float* b1      = (const float*)d_in[4]; // [K][64]
    const float* gamma   = (const float*)d_in[5];
    const float* beta    = (const float*)d_in[6];
    const float* W2      = (const float*)d_in[7]; // [K][64][2]
    const float* b2      = (const float*)d_in[8]; // [K][2]
    const float* Wg      = (const float*)d_in[9]; // [256][4]
    const float* bg      = (const float*)d_in[10];
    float* out = (float*)d_out;

    const int N = NN, E = EE, K = KEXP;

    char* ws = (char*)d_ws;
    size_t off = 0;
    auto alloc = [&](size_t bytes) -> void* {
        void* p = (void*)(ws + off);
        off += (bytes + 255) & ~(size_t)255;
        return p;
    };
    int*   cnt     = (int*)alloc((size_t)K * N * 4);
    int*   rowptr  = (int*)alloc((size_t)K * (N + 1) * 4);
    int*   cursor  = (int*)alloc((size_t)K * N * 4);
    float* dis     = (float*)alloc((size_t)K * N * 4);
    int*   bsum    = (int*)alloc((size_t)K * NBLK * 4);
    int*   bcur    = (int*)alloc((size_t)K * NBUCK * 4);
    int*   adj     = (int*)alloc((size_t)K * E * 4);
    float* h       = (float*)alloc((size_t)N * 64 * 4);
    float* x       = (float*)alloc((size_t)N * 64 * 4);
    float* h2      = (float*)alloc((size_t)N * 2 * 4);
    float* agg2    = (float*)alloc((size_t)K * N * 2 * 4);
    float* accum   = (float*)alloc((size_t)K * 128 * 4);
    float* mu_istd = (float*)alloc(128 * 4);
    (void)ws_size; (void)in_sizes; (void)n_in; (void)out_size;

    // bstream (K*E*8 = 51.2 MB) aliases h+x (2 * 25.6 MB, contiguous):
    // only used before gemm1 writes h.
    unsigned long long* bstream = (unsigned long long*)h;

    const int egrid = (E + 255) / 256;

    // ---- batched CSR build for all experts (bucketed two-pass sort) ----
    hipMemsetAsync(cnt, 0, (size_t)K * N * 4, stream);
    hipMemsetAsync(accum, 0, (size_t)K * 128 * 4, stream);
    deg_kernel<<<dim3(egrid, K), 256, 0, stream>>>(edge, cnt, N, E);
    dis_kernel<<<(K * N + 255) / 256, 256, 0, stream>>>(cnt, dis, K * N);
    scan_blocks<<<dim3(NBLK, K), 256, 0, stream>>>(cnt, rowptr, bsum, N);
    scan_bsum<<<K, 512, 0, stream>>>(bsum, rowptr, NBLK, N, E);
    scan_add<<<dim3(NBLK, K), 256, 0, stream>>>(rowptr, bsum, cursor, N);
    binit_kernel<<<(K * NBUCK + 255) / 256, 256, 0, stream>>>(rowptr, bcur, N);
    partition_kernel<<<dim3((E + PCHUNK - 1) / PCHUNK, K), 256, 0, stream>>>(edge, bcur, bstream, N, E);
    bucket_scatter<<<dim3(NBUCK, K, ZCH), 256, 0, stream>>>(rowptr, bstream, cursor, adj, N, E);

    // ---- per-expert pipeline ----
    for (int k = 0; k < K; k++) {
        const int* rp = rowptr + (size_t)k * (N + 1);
        const int* aj = adj + (size_t)k * E;
        const float* dk = dis + (size_t)k * N;
        gemm1_kernel<<<(N + 63) / 64, 256, 0, stream>>>(
            flatten, W1 + (size_t)k * 256 * 64, h, N);
        gather1<<<(N + 3) / 4, 256, 0, stream>>>(
            rp, aj, dk, h, b1 + (size_t)k * 64, x, N);
        stats_kernel<<<400, 256, 0, stream>>>(x, accum + (size_t)k * 128, N);
        stats_fin<<<1, 64, 0, stream>>>(accum + (size_t)k * 128, mu_istd, N);
        bn_gemm2<<<(int)(((size_t)N * 64 + 255) / 256), 256, 0, stream>>>(
            x, mu_istd, gamma + (size_t)k * 64, beta + (size_t)k * 64,
            W2 + (size_t)k * 128, h2, N);
        gather2<<<(N + 255) / 256, 256, 0, stream>>>(
            rp, aj, dk, h2, b2 + (size_t)k * 2, agg2 + (size_t)k * N * 2, N);
    }
    final_kernel<<<(int)(((size_t)N * 64 + 255) / 256), 256, 0, stream>>>(
        moe, Wg, bg, agg2, out, N);
}

// Round 5
// 1317.886 us; speedup vs baseline: 3.2306x; 1.2547x over previous
//
#include <hip/hip_runtime.h>
#include <math.h>

#define NN 100000
#define KEXP 4
#define EE 1600000
#define EPSV 1e-5f
#define BSHIFT 9
#define BSIZE 512
#define NBUCK 196       // ceil(100000/512)
#define PCHUNK 16384    // edges per block in hist/partition kernels

// ---------------- bucket histogram (196 bins, LDS -> 1 global atomic/bin) --
__global__ __launch_bounds__(256) void bucket_hist(const int* __restrict__ edge,
                                                   int* __restrict__ bknt, int E) {
    int k = blockIdx.y;
    int cbase = blockIdx.x * PCHUNK;
    const int* dp = edge + (size_t)k * 2 * E + E;
    __shared__ int hist[NBUCK];
    for (int i = threadIdx.x; i < NBUCK; i += 256) hist[i] = 0;
    __syncthreads();
    int cend = cbase + PCHUNK;
    if (cend > E) cend = E;
    for (int e = cbase + (int)threadIdx.x; e < cend; e += 256)
        atomicAdd(&hist[dp[e] >> BSHIFT], 1);
    __syncthreads();
    for (int i = threadIdx.x; i < NBUCK; i += 256) {
        int c = hist[i];
        if (c) atomicAdd(&bknt[k * NBUCK + i], c);
    }
}

// ---------------- scan bucket counts -> bases (+ init partition cursors) --
__global__ __launch_bounds__(256) void bucket_scan(const int* __restrict__ bknt,
                                                   int* __restrict__ bbase,
                                                   int* __restrict__ bcur,
                                                   int* __restrict__ rowptr,
                                                   int n, int E) {
    int k = blockIdx.x;
    int t = threadIdx.x;
    __shared__ int sd[256];
    int v = (t < NBUCK) ? bknt[k * NBUCK + t] : 0;
    sd[t] = v;
    __syncthreads();
    for (int o = 1; o < 256; o <<= 1) {
        int x = (t >= o) ? sd[t - o] : 0;
        __syncthreads();
        sd[t] += x;
        __syncthreads();
    }
    if (t < NBUCK) {
        int e = sd[t] - v;  // exclusive
        bbase[k * (NBUCK + 1) + t] = e;
        bcur[k * NBUCK + t] = e;
    }
    if (t == 0) {
        bbase[k * (NBUCK + 1) + NBUCK] = E;
        rowptr[(size_t)k * (n + 1) + n] = E;
    }
}

// ---------------- partition: LDS multi-split into bucket streams ----------
__global__ __launch_bounds__(256) void partition_kernel(const int* __restrict__ edge,
                                                        int* __restrict__ bcur,
                                                        unsigned long long* __restrict__ bstream,
                                                        int E) {
    int k = blockIdx.y;
    int cbase = blockIdx.x * PCHUNK;
    const int* sp = edge + (size_t)k * 2 * E;
    const int* dp = sp + E;
    __shared__ int hist[NBUCK];
    __shared__ int base[NBUCK];
    for (int i = threadIdx.x; i < NBUCK; i += 256) hist[i] = 0;
    __syncthreads();
    int cend = cbase + PCHUNK;
    if (cend > E) cend = E;
    for (int e = cbase + (int)threadIdx.x; e < cend; e += 256) {
        atomicAdd(&hist[dp[e] >> BSHIFT], 1);
    }
    __syncthreads();
    for (int i = threadIdx.x; i < NBUCK; i += 256) {
        int c = hist[i];
        base[i] = c ? atomicAdd(&bcur[k * NBUCK + i], c) : 0;
        hist[i] = 0;
    }
    __syncthreads();
    unsigned long long* bs = bstream + (size_t)k * E;
    for (int e = cbase + (int)threadIdx.x; e < cend; e += 256) {
        int s = sp[e];
        int d = dp[e];
        int b = d >> BSHIFT;
        int r = atomicAdd(&hist[b], 1);
        bs[base[b] + r] = ((unsigned long long)(unsigned)d << 32) | (unsigned)s;
    }
}

// ---------------- per-bucket: degree hist + scan + rowptr + dis + scatter --
// All degree counting / prefix / cursor atomics live in LDS. One block per
// (bucket, expert); the bucket's edges are contiguous in bstream and its adj
// output window is a contiguous ~32 KB region.
__global__ __launch_bounds__(256) void bucket_build(const int* __restrict__ bbase,
                                                    const unsigned long long* __restrict__ bstream,
                                                    int* __restrict__ rowptr,
                                                    float* __restrict__ dis,
                                                    int* __restrict__ adj,
                                                    int n, int E) {
    int k = blockIdx.y;
    int b = blockIdx.x;
    int nb = b << BSHIFT;
    int t = threadIdx.x;
    __shared__ int hist[BSIZE];
    __shared__ int curx[BSIZE];
    __shared__ int tmp[256];
    hist[t] = 0;
    hist[t + 256] = 0;
    __syncthreads();
    int beg = bbase[k * (NBUCK + 1) + b];
    int end = bbase[k * (NBUCK + 1) + b + 1];
    const unsigned long long* bs = bstream + (size_t)k * E;
    for (int p = beg + t; p < end; p += 256) {
        int d = (int)(bs[p] >> 32);
        atomicAdd(&hist[d - nb], 1);
    }
    __syncthreads();
    int a0 = hist[2 * t], a1 = hist[2 * t + 1];
    tmp[t] = a0 + a1;
    __syncthreads();
    for (int o = 1; o < 256; o <<= 1) {
        int x = (t >= o) ? tmp[t - o] : 0;
        __syncthreads();
        tmp[t] += x;
        __syncthreads();
    }
    int ex = tmp[t] - (a0 + a1);  // exclusive prefix over pairs
    int c0 = beg + ex;
    int c1 = c0 + a0;
    curx[2 * t] = c0;
    curx[2 * t + 1] = c1;
    int* rp = rowptr + (size_t)k * (n + 1);
    float* dk = dis + (size_t)k * n;
    int node0 = nb + 2 * t, node1 = nb + 2 * t + 1;
    if (node0 < n) { rp[node0] = c0; dk[node0] = rsqrtf((float)a0 + 2.0f); }
    if (node1 < n) { rp[node1] = c1; dk[node1] = rsqrtf((float)a1 + 2.0f); }
    __syncthreads();
    int* aj = adj + (size_t)k * E;
    for (int p = beg + t; p < end; p += 256) {
        unsigned long long pk = bs[p];
        int d = (int)(pk >> 32);
        int s = (int)(pk & 0xffffffffull);
        int pos = atomicAdd(&curx[d - nb], 1);
        aj[pos] = s;
    }
}

// ---------------- GEMM1: h = A @ W (M x 256 x 64) ----------------
__global__ __launch_bounds__(256) void gemm1_kernel(
    const float* __restrict__ A,    // [M,256]
    const float* __restrict__ W,    // [256,64]
    float* __restrict__ h,          // [M,64]
    int M) {
    __shared__ __align__(16) float As[64][65];
    __shared__ __align__(16) float Ws[64][68];
    int t = threadIdx.x;
    int row0 = blockIdx.x * 64;
    int tr = t >> 4;   // 0..15
    int tc = t & 15;   // 0..15
    float acc[4][4] = {{0.f}};

    for (int kc = 0; kc < 256; kc += 64) {
        for (int i = 0; i < 4; i++) {
            int fid = t + i * 256;
            int r = fid >> 4;
            int c4 = (fid & 15) << 2;
            int row = row0 + r;
            float4 v = make_float4(0.f, 0.f, 0.f, 0.f);
            if (row < M) v = *(const float4*)&A[(size_t)row * 256 + kc + c4];
            As[r][c4] = v.x; As[r][c4 + 1] = v.y; As[r][c4 + 2] = v.z; As[r][c4 + 3] = v.w;
        }
        for (int i = 0; i < 4; i++) {
            int fid = t + i * 256;
            int r = fid >> 4;
            int c4 = (fid & 15) << 2;
            float4 v = *(const float4*)&W[(size_t)(kc + r) * 64 + c4];
            *(float4*)&Ws[r][c4] = v;
        }
        __syncthreads();
        for (int kk = 0; kk < 64; kk++) {
            float a0 = As[tr * 4 + 0][kk];
            float a1 = As[tr * 4 + 1][kk];
            float a2 = As[tr * 4 + 2][kk];
            float a3 = As[tr * 4 + 3][kk];
            float4 w = *(const float4*)&Ws[kk][tc * 4];
            acc[0][0] += a0 * w.x; acc[0][1] += a0 * w.y; acc[0][2] += a0 * w.z; acc[0][3] += a0 * w.w;
            acc[1][0] += a1 * w.x; acc[1][1] += a1 * w.y; acc[1][2] += a1 * w.z; acc[1][3] += a1 * w.w;
            acc[2][0] += a2 * w.x; acc[2][1] += a2 * w.y; acc[2][2] += a2 * w.z; acc[2][3] += a2 * w.w;
            acc[3][0] += a3 * w.x; acc[3][1] += a3 * w.y; acc[3][2] += a3 * w.z; acc[3][3] += a3 * w.w;
        }
        __syncthreads();
    }
    for (int i = 0; i < 4; i++) {
        int row = row0 + tr * 4 + i;
        if (row >= M) continue;
        float4 v = make_float4(acc[i][0], acc[i][1], acc[i][2], acc[i][3]);
        *(float4*)&h[(size_t)row * 64 + tc * 4] = v;
    }
}

// ---------------- gather agg1: wave per node, lane = feature; fused relu ----
__global__ __launch_bounds__(256) void gather1(const int* __restrict__ rowptr,
                                               const int* __restrict__ adj,
                                               const float* __restrict__ dis,
                                               const float* __restrict__ h,
                                               const float* __restrict__ b1,
                                               float* __restrict__ x, int n) {
    int node = blockIdx.x * 4 + (threadIdx.x >> 6);
    int lane = threadIdx.x & 63;
    if (node >= n) return;
    int beg = rowptr[node], end = rowptr[node + 1];
    float acc = 0.f;
    int j = beg;
    for (; j + 2 <= end; j += 2) {
        int s0 = adj[j], s1 = adj[j + 1];
        float d0 = dis[s0], d1 = dis[s1];
        float v0 = h[(size_t)s0 * 64 + lane];
        float v1 = h[(size_t)s1 * 64 + lane];
        acc += d0 * v0;
        acc += d1 * v1;
    }
    if (j < end) {
        int s0 = adj[j];
        acc += dis[s0] * h[(size_t)s0 * 64 + lane];
    }
    float dn = dis[node];
    float val = dn * acc + 2.f * dn * dn * h[(size_t)node * 64 + lane] + b1[lane];
    x[(size_t)node * 64 + lane] = fmaxf(val, 0.f);
}

// ---------------- BN column stats: grid-stride + atomic finalize ----------
__global__ __launch_bounds__(256) void stats_kernel(const float* __restrict__ x,
                                                    float* __restrict__ accum, int n) {
    int c = threadIdx.x & 63;
    int w = threadIdx.x >> 6;
    float s = 0.f, q = 0.f;
    for (int r = blockIdx.x * 4 + w; r < n; r += gridDim.x * 4) {
        float v = x[(size_t)r * 64 + c];
        s += v; q += v * v;
    }
    __shared__ float ls[4][64];
    __shared__ float lq[4][64];
    ls[w][c] = s; lq[w][c] = q;
    __syncthreads();
    if (threadIdx.x < 64) {
        float S = ls[0][c] + ls[1][c] + ls[2][c] + ls[3][c];
        float Q = lq[0][c] + lq[1][c] + lq[2][c] + lq[3][c];
        unsafeAtomicAdd(&accum[c], S);
        unsafeAtomicAdd(&accum[64 + c], Q);
    }
}

__global__ void stats_fin(const float* __restrict__ accum,
                          float* __restrict__ mu_istd, int M) {
    int c = threadIdx.x;  // 64 threads
    float mu = accum[c] / (float)M;
    float var = accum[64 + c] / (float)M - mu * mu;
    mu_istd[c] = mu;
    mu_istd[64 + c] = rsqrtf(var + EPSV);
}

// ---------------- BN apply + GEMM2 (64 -> 2) ----------------
__global__ __launch_bounds__(256) void bn_gemm2(const float* __restrict__ x,
                                                const float* __restrict__ mu_istd,
                                                const float* __restrict__ g,
                                                const float* __restrict__ bt,
                                                const float* __restrict__ W2,
                                                float* __restrict__ h2, int M) {
    int wid = (int)((blockIdx.x * (size_t)blockDim.x + threadIdx.x) >> 6);
    int c = threadIdx.x & 63;
    if (wid >= M) return;
    float v = x[(size_t)wid * 64 + c];
    v = (v - mu_istd[c]) * mu_istd[64 + c] * g[c] + bt[c];
    float p0 = v * W2[c * 2];
    float p1 = v * W2[c * 2 + 1];
    for (int off = 32; off; off >>= 1) {
        p0 += __shfl_down(p0, off);
        p1 += __shfl_down(p1, off);
    }
    if (c == 0) {
        float2 o = make_float2(p0, p1);
        *(float2*)&h2[(size_t)wid * 2] = o;
    }
}

// ---------------- gather agg2: thread per node ----------------
__global__ __launch_bounds__(256) void gather2(const int* __restrict__ rowptr,
                                               const int* __restrict__ adj,
                                               const float* __restrict__ dis,
                                               const float* __restrict__ h2,
                                               const float* __restrict__ b2,
                                               float* __restrict__ agg2, int n) {
    int node = blockIdx.x * 256 + threadIdx.x;
    if (node >= n) return;
    int beg = rowptr[node], end = rowptr[node + 1];
    float a0 = 0.f, a1 = 0.f;
    int j = beg;
    for (; j + 2 <= end; j += 2) {
        int s0 = adj[j], s1 = adj[j + 1];
        float d0 = dis[s0], d1 = dis[s1];
        float2 v0 = *(const float2*)&h2[(size_t)s0 * 2];
        float2 v1 = *(const float2*)&h2[(size_t)s1 * 2];
        a0 += d0 * v0.x + d1 * v1.x;
        a1 += d0 * v0.y + d1 * v1.y;
    }
    if (j < end) {
        int s0 = adj[j];
        float d0 = dis[s0];
        float2 v0 = *(const float2*)&h2[(size_t)s0 * 2];
        a0 += d0 * v0.x;
        a1 += d0 * v0.y;
    }
    float dn = dis[node];
    float sc = 2.f * dn * dn;
    float2 hv = *(const float2*)&h2[(size_t)node * 2];
    float2 o;
    o.x = dn * a0 + sc * hv.x + b2[0];
    o.y = dn * a1 + sc * hv.y + b2[1];
    *(float2*)&agg2[(size_t)node * 2] = o;
}

// ---------------- gating + mixture output ----------------
__global__ __launch_bounds__(256) void final_kernel(const float* __restrict__ moe,
                                                    const float* __restrict__ Wg,
                                                    const float* __restrict__ bg,
                                                    const float* __restrict__ agg2,  // [K][N][2]
                                                    float* __restrict__ out, int M) {
    int n = (int)((blockIdx.x * (size_t)blockDim.x + threadIdx.x) >> 6);
    int lane = threadIdx.x & 63;
    if (n >= M) return;
    float4 mf = *(const float4*)&moe[(size_t)n * 256 + lane * 4];
    const float* wr = &Wg[lane * 16];
    float a0 = mf.x * wr[0] + mf.y * wr[4] + mf.z * wr[8] + mf.w * wr[12];
    float a1 = mf.x * wr[1] + mf.y * wr[5] + mf.z * wr[9] + mf.w * wr[13];
    float a2 = mf.x * wr[2] + mf.y * wr[6] + mf.z * wr[10] + mf.w * wr[14];
    float a3 = mf.x * wr[3] + mf.y * wr[7] + mf.z * wr[11] + mf.w * wr[15];
    for (int mask = 1; mask < 64; mask <<= 1) {
        a0 += __shfl_xor(a0, mask);
        a1 += __shfl_xor(a1, mask);
        a2 += __shfl_xor(a2, mask);
        a3 += __shfl_xor(a3, mask);
    }
    if (lane == 0) {
        float gl[4] = {a0 + bg[0], a1 + bg[1], a2 + bg[2], a3 + bg[3]};
        float m = fmaxf(fmaxf(gl[0], gl[1]), fmaxf(gl[2], gl[3]));
        float w[4];
        float wsum = 0.f;
        for (int kk = 0; kk < 4; kk++) { w[kk] = expf(gl[kk] - m); wsum += w[kk]; }
        float o0 = 0.f, o1 = 0.f, q0 = 0.f, q1 = 0.f;
        for (int kk = 0; kk < 4; kk++) {
            float l0 = agg2[((size_t)kk * M + n) * 2];
            float l1 = agg2[((size_t)kk * M + n) * 2 + 1];
            float mm = fmaxf(l0, l1);
            float lse = mm + logf(expf(l0 - mm) + expf(l1 - mm));
            float lp0 = l0 - lse, lp1 = l1 - lse;
            float wk = w[kk] / wsum;
            o0 += wk * lp0; o1 += wk * lp1;
            q0 += wk * expf(lp0); q1 += wk * expf(lp1);
        }
        out[(size_t)n * 2] = o0;
        out[(size_t)n * 2 + 1] = o1;
        out[(size_t)2 * M + n * 2] = q0;
        out[(size_t)2 * M + n * 2 + 1] = q1;
    }
}

extern "C" void kernel_launch(void* const* d_in, const int* in_sizes, int n_in,
                              void* d_out, int out_size, void* d_ws, size_t ws_size,
                              hipStream_t stream) {
    const float* flatten = (const float*)d_in[0];
    const float* moe     = (const float*)d_in[1];
    const int*   edge    = (const int*)d_in[2];   // [K][2][E]
    const float* W1      = (const float*)d_in[3]; // [K][256][64]
    const float* b1      = (const float*)d_in[4]; // [K][64]
    const float* gamma   = (const float*)d_in[5];
    const float* beta    = (const float*)d_in[6];
    const float* W2      = (const float*)d_in[7]; // [K][64][2]
    const float* b2      = (const float*)d_in[8]; // [K][2]
    const float* Wg      = (const float*)d_in[9]; // [256][4]
    const float* bg      = (const float*)d_in[10];
    float* out = (float*)d_out;

    const int N = NN, E = EE, K = KEXP;

    char* ws = (char*)d_ws;
    size_t off = 0;
    auto alloc = [&](size_t bytes) -> void* {
        void* p = (void*)(ws + off);
        off += (bytes + 255) & ~(size_t)255;
        return p;
    };
    int*   rowptr  = (int*)alloc((size_t)K * (N + 1) * 4);
    float* dis     = (float*)alloc((size_t)K * N * 4);
    int*   bknt    = (int*)alloc((size_t)K * NBUCK * 4);
    int*   bbase   = (int*)alloc((size_t)K * (NBUCK + 1) * 4);
    int*   bcur    = (int*)alloc((size_t)K * NBUCK * 4);
    int*   adj     = (int*)alloc((size_t)K * E * 4);
    float* h       = (float*)alloc((size_t)N * 64 * 4);
    float* x       = (float*)alloc((size_t)N * 64 * 4);
    float* h2      = (float*)alloc((size_t)N * 2 * 4);
    float* agg2    = (float*)alloc((size_t)K * N * 2 * 4);
    float* accum   = (float*)alloc((size_t)K * 128 * 4);
    float* mu_istd = (float*)alloc(128 * 4);
    (void)ws_size; (void)in_sizes; (void)n_in; (void)out_size;

    // bstream (K*E*8 = 51.2 MB) aliases h+x (2 * 25.6 MB, contiguous):
    // only used before gemm1 writes h.
    unsigned long long* bstream = (unsigned long long*)h;

    const int pgrid = (E + PCHUNK - 1) / PCHUNK;

    // ---- batched CSR build (bucket sort; all per-node work in LDS) ----
    hipMemsetAsync(bknt, 0, (size_t)K * NBUCK * 4, stream);
    hipMemsetAsync(accum, 0, (size_t)K * 128 * 4, stream);
    bucket_hist<<<dim3(pgrid, K), 256, 0, stream>>>(edge, bknt, E);
    bucket_scan<<<K, 256, 0, stream>>>(bknt, bbase, bcur, rowptr, N, E);
    partition_kernel<<<dim3(pgrid, K), 256, 0, stream>>>(edge, bcur, bstream, E);
    bucket_build<<<dim3(NBUCK, K), 256, 0, stream>>>(bbase, bstream, rowptr, dis, adj, N, E);

    // ---- per-expert pipeline ----
    for (int k = 0; k < K; k++) {
        const int* rp = rowptr + (size_t)k * (N + 1);
        const int* aj = adj + (size_t)k * E;
        const float* dk = dis + (size_t)k * N;
        gemm1_kernel<<<(N + 63) / 64, 256, 0, stream>>>(
            flatten, W1 + (size_t)k * 256 * 64, h, N);
        gather1<<<(N + 3) / 4, 256, 0, stream>>>(
            rp, aj, dk, h, b1 + (size_t)k * 64, x, N);
        stats_kernel<<<400, 256, 0, stream>>>(x, accum + (size_t)k * 128, N);
        stats_fin<<<1, 64, 0, stream>>>(accum + (size_t)k * 128, mu_istd, N);
        bn_gemm2<<<(int)(((size_t)N * 64 + 255) / 256), 256, 0, stream>>>(
            x, mu_istd, gamma + (size_t)k * 64, beta + (size_t)k * 64,
            W2 + (size_t)k * 128, h2, N);
        gather2<<<(N + 255) / 256, 256, 0, stream>>>(
            rp, aj, dk, h2, b2 + (size_t)k * 2, agg2 + (size_t)k * N * 2, N);
    }
    final_kernel<<<(int)(((size_t)N * 64 + 255) / 256), 256, 0, stream>>>(
        moe, Wg, bg, agg2, out, N);
}

// Round 6
// 1106.796 us; speedup vs baseline: 3.8467x; 1.1907x over previous
//
#include <hip/hip_runtime.h>
#include <math.h>

#define NN 100000
#define KEXP 4
#define EE 1600000
#define EPSV 1e-5f
#define BSHIFT 9
#define BSIZE 512
#define NBUCK 196       // ceil(100000/512)
#define PCHUNK 16384    // edges per block in hist/partition kernels
#define SLOTS 64        // hashed stat accumulator slots

__device__ __forceinline__ unsigned short f2bf(float f) {
    unsigned u = __float_as_uint(f);
    return (unsigned short)((u + 0x7fff + ((u >> 16) & 1)) >> 16);
}
__device__ __forceinline__ float bf_lo(unsigned u) { return __uint_as_float(u << 16); }
__device__ __forceinline__ float bf_hi(unsigned u) { return __uint_as_float(u & 0xffff0000u); }

// ---------------- bucket histogram (196 bins, LDS -> 1 global atomic/bin) --
__global__ __launch_bounds__(256) void bucket_hist(const int* __restrict__ edge,
                                                   int* __restrict__ bknt, int E) {
    int k = blockIdx.y;
    int cbase = blockIdx.x * PCHUNK;
    const int* dp = edge + (size_t)k * 2 * E + E;
    __shared__ int hist[NBUCK];
    for (int i = threadIdx.x; i < NBUCK; i += 256) hist[i] = 0;
    __syncthreads();
    int cend = cbase + PCHUNK;
    if (cend > E) cend = E;
    for (int e = cbase + (int)threadIdx.x; e < cend; e += 256)
        atomicAdd(&hist[dp[e] >> BSHIFT], 1);
    __syncthreads();
    for (int i = threadIdx.x; i < NBUCK; i += 256) {
        int c = hist[i];
        if (c) atomicAdd(&bknt[k * NBUCK + i], c);
    }
}

// ---------------- scan bucket counts -> bases (+ init partition cursors) --
__global__ __launch_bounds__(256) void bucket_scan(const int* __restrict__ bknt,
                                                   int* __restrict__ bbase,
                                                   int* __restrict__ bcur,
                                                   int* __restrict__ rowptr,
                                                   int n, int E) {
    int k = blockIdx.x;
    int t = threadIdx.x;
    __shared__ int sd[256];
    int v = (t < NBUCK) ? bknt[k * NBUCK + t] : 0;
    sd[t] = v;
    __syncthreads();
    for (int o = 1; o < 256; o <<= 1) {
        int x = (t >= o) ? sd[t - o] : 0;
        __syncthreads();
        sd[t] += x;
        __syncthreads();
    }
    if (t < NBUCK) {
        int e = sd[t] - v;  // exclusive
        bbase[k * (NBUCK + 1) + t] = e;
        bcur[k * NBUCK + t] = e;
    }
    if (t == 0) {
        bbase[k * (NBUCK + 1) + NBUCK] = E;
        rowptr[(size_t)k * (n + 1) + n] = E;
    }
}

// ---------------- partition: LDS multi-split into packed-u32 bucket streams
// pack = (d&511)<<17 | s  (s < 2^17, bucket-local d in 9 bits)
__global__ __launch_bounds__(256) void partition_kernel(const int* __restrict__ edge,
                                                        int* __restrict__ bcur,
                                                        unsigned* __restrict__ bstream,
                                                        int E) {
    int k = blockIdx.y;
    int cbase = blockIdx.x * PCHUNK;
    const int* sp = edge + (size_t)k * 2 * E;
    const int* dp = sp + E;
    __shared__ int hist[NBUCK];
    __shared__ int base[NBUCK];
    for (int i = threadIdx.x; i < NBUCK; i += 256) hist[i] = 0;
    __syncthreads();
    int cend = cbase + PCHUNK;
    if (cend > E) cend = E;
    for (int e = cbase + (int)threadIdx.x; e < cend; e += 256) {
        atomicAdd(&hist[dp[e] >> BSHIFT], 1);
    }
    __syncthreads();
    for (int i = threadIdx.x; i < NBUCK; i += 256) {
        int c = hist[i];
        base[i] = c ? atomicAdd(&bcur[k * NBUCK + i], c) : 0;
        hist[i] = 0;
    }
    __syncthreads();
    unsigned* bs = bstream + (size_t)k * E;
    for (int e = cbase + (int)threadIdx.x; e < cend; e += 256) {
        int s = sp[e];
        int d = dp[e];
        int b = d >> BSHIFT;
        int r = atomicAdd(&hist[b], 1);
        bs[base[b] + r] = ((unsigned)(d & (BSIZE - 1)) << 17) | (unsigned)s;
    }
}

// ---------------- per-bucket: degree hist + scan + rowptr + dis + scatter --
__global__ __launch_bounds__(256) void bucket_build(const int* __restrict__ bbase,
                                                    const unsigned* __restrict__ bstream,
                                                    int* __restrict__ rowptr,
                                                    float* __restrict__ dis,
                                                    int* __restrict__ adj,
                                                    int n, int E) {
    int k = blockIdx.y;
    int b = blockIdx.x;
    int nb = b << BSHIFT;
    int t = threadIdx.x;
    __shared__ int hist[BSIZE];
    __shared__ int curx[BSIZE];
    __shared__ int tmp[256];
    hist[t] = 0;
    hist[t + 256] = 0;
    __syncthreads();
    int beg = bbase[k * (NBUCK + 1) + b];
    int end = bbase[k * (NBUCK + 1) + b + 1];
    const unsigned* bs = bstream + (size_t)k * E;
    for (int p = beg + t; p < end; p += 256) {
        atomicAdd(&hist[bs[p] >> 17], 1);
    }
    __syncthreads();
    int a0 = hist[2 * t], a1 = hist[2 * t + 1];
    tmp[t] = a0 + a1;
    __syncthreads();
    for (int o = 1; o < 256; o <<= 1) {
        int x = (t >= o) ? tmp[t - o] : 0;
        __syncthreads();
        tmp[t] += x;
        __syncthreads();
    }
    int ex = tmp[t] - (a0 + a1);  // exclusive prefix over pairs
    int c0 = beg + ex;
    int c1 = c0 + a0;
    curx[2 * t] = c0;
    curx[2 * t + 1] = c1;
    int* rp = rowptr + (size_t)k * (n + 1);
    float* dk = dis + (size_t)k * n;
    int node0 = nb + 2 * t, node1 = nb + 2 * t + 1;
    if (node0 < n) { rp[node0] = c0; dk[node0] = rsqrtf((float)a0 + 2.0f); }
    if (node1 < n) { rp[node1] = c1; dk[node1] = rsqrtf((float)a1 + 2.0f); }
    __syncthreads();
    int* aj = adj + (size_t)k * E;
    for (int p = beg + t; p < end; p += 256) {
        unsigned pk = bs[p];
        int pos = atomicAdd(&curx[pk >> 17], 1);
        aj[pos] = (int)(pk & 0x1FFFFu);
    }
}

// ---------------- GEMM1: h = A @ W (M x 256 x 64), output bf16 ----------
__global__ __launch_bounds__(256) void gemm1_kernel(
    const float* __restrict__ A,    // [M,256]
    const float* __restrict__ W,    // [256,64]
    unsigned short* __restrict__ hbf,  // [M,64] bf16
    int M) {
    __shared__ __align__(16) float As[64][65];
    __shared__ __align__(16) float Ws[64][68];
    int t = threadIdx.x;
    int row0 = blockIdx.x * 64;
    int tr = t >> 4;   // 0..15
    int tc = t & 15;   // 0..15
    float acc[4][4] = {{0.f}};

    for (int kc = 0; kc < 256; kc += 64) {
        for (int i = 0; i < 4; i++) {
            int fid = t + i * 256;
            int r = fid >> 4;
            int c4 = (fid & 15) << 2;
            int row = row0 + r;
            float4 v = make_float4(0.f, 0.f, 0.f, 0.f);
            if (row < M) v = *(const float4*)&A[(size_t)row * 256 + kc + c4];
            As[r][c4] = v.x; As[r][c4 + 1] = v.y; As[r][c4 + 2] = v.z; As[r][c4 + 3] = v.w;
        }
        for (int i = 0; i < 4; i++) {
            int fid = t + i * 256;
            int r = fid >> 4;
            int c4 = (fid & 15) << 2;
            float4 v = *(const float4*)&W[(size_t)(kc + r) * 64 + c4];
            *(float4*)&Ws[r][c4] = v;
        }
        __syncthreads();
        for (int kk = 0; kk < 64; kk++) {
            float a0 = As[tr * 4 + 0][kk];
            float a1 = As[tr * 4 + 1][kk];
            float a2 = As[tr * 4 + 2][kk];
            float a3 = As[tr * 4 + 3][kk];
            float4 w = *(const float4*)&Ws[kk][tc * 4];
            acc[0][0] += a0 * w.x; acc[0][1] += a0 * w.y; acc[0][2] += a0 * w.z; acc[0][3] += a0 * w.w;
            acc[1][0] += a1 * w.x; acc[1][1] += a1 * w.y; acc[1][2] += a1 * w.z; acc[1][3] += a1 * w.w;
            acc[2][0] += a2 * w.x; acc[2][1] += a2 * w.y; acc[2][2] += a2 * w.z; acc[2][3] += a2 * w.w;
            acc[3][0] += a3 * w.x; acc[3][1] += a3 * w.y; acc[3][2] += a3 * w.z; acc[3][3] += a3 * w.w;
        }
        __syncthreads();
    }
    for (int i = 0; i < 4; i++) {
        int row = row0 + tr * 4 + i;
        if (row >= M) continue;
        ushort4 o;
        o.x = f2bf(acc[i][0]); o.y = f2bf(acc[i][1]);
        o.z = f2bf(acc[i][2]); o.w = f2bf(acc[i][3]);
        *(ushort4*)&hbf[(size_t)row * 64 + 4 * tc] = o;
    }
}

// ---------------- gather agg1: wave per node, 2 edges/iter (lane halves),
// bf16 h, fused relu + BN stats (hashed-slot global accumulate) ----------
__global__ __launch_bounds__(256) void gather1(const int* __restrict__ rowptr,
                                               const int* __restrict__ adj,
                                               const float* __restrict__ dis,
                                               const unsigned short* __restrict__ hbf,
                                               const float* __restrict__ b1,
                                               float* __restrict__ x,
                                               float* __restrict__ accum, int n) {
    __shared__ float ls[4][64];
    __shared__ float lq[4][64];
    ((float*)ls)[threadIdx.x] = 0.f;
    ((float*)lq)[threadIdx.x] = 0.f;
    __syncthreads();
    int w = threadIdx.x >> 6;
    int node = blockIdx.x * 4 + w;
    int lane = threadIdx.x & 63;
    int half = lane >> 5;      // which edge of the pair
    int p = lane & 31;         // feature pair index (features 2p, 2p+1)
    if (node < n) {
        int beg = rowptr[node], end = rowptr[node + 1];
        float ax = 0.f, ay = 0.f;
        int j = beg + half;
        for (; j + 2 < end; j += 4) {
            int s0 = adj[j], s1 = adj[j + 2];
            float d0 = dis[s0], d1 = dis[s1];
            unsigned u0 = *(const unsigned*)&hbf[(size_t)s0 * 64 + 2 * p];
            unsigned u1 = *(const unsigned*)&hbf[(size_t)s1 * 64 + 2 * p];
            ax += d0 * bf_lo(u0) + d1 * bf_lo(u1);
            ay += d0 * bf_hi(u0) + d1 * bf_hi(u1);
        }
        if (j < end) {
            int s0 = adj[j];
            float d0 = dis[s0];
            unsigned u0 = *(const unsigned*)&hbf[(size_t)s0 * 64 + 2 * p];
            ax += d0 * bf_lo(u0);
            ay += d0 * bf_hi(u0);
        }
        ax += __shfl_xor(ax, 32);
        ay += __shfl_xor(ay, 32);
        float dn = dis[node];
        float sc = 2.f * dn * dn;
        unsigned us = *(const unsigned*)&hbf[(size_t)node * 64 + 2 * p];
        float vx = dn * ax + sc * bf_lo(us) + b1[2 * p];
        float vy = dn * ay + sc * bf_hi(us) + b1[2 * p + 1];
        vx = fmaxf(vx, 0.f);
        vy = fmaxf(vy, 0.f);
        if (half == 0) {
            *(float2*)&x[(size_t)node * 64 + 2 * p] = make_float2(vx, vy);
            ls[w][2 * p] = vx;
            ls[w][2 * p + 1] = vy;
            lq[w][2 * p] = vx * vx;
            lq[w][2 * p + 1] = vy * vy;
        }
    }
    __syncthreads();
    if (threadIdx.x < 64) {
        int c = threadIdx.x;
        float S = ls[0][c] + ls[1][c] + ls[2][c] + ls[3][c];
        float Q = lq[0][c] + lq[1][c] + lq[2][c] + lq[3][c];
        float* slot = accum + (size_t)(blockIdx.x & (SLOTS - 1)) * 128;
        unsafeAtomicAdd(&slot[c], S);
        unsafeAtomicAdd(&slot[64 + c], Q);
    }
}

__global__ void stats_fin(const float* __restrict__ accum,
                          float* __restrict__ mu_istd, int M) {
    int c = threadIdx.x;  // 64 threads
    float S = 0.f, Q = 0.f;
    for (int s = 0; s < SLOTS; s++) {
        S += accum[(size_t)s * 128 + c];
        Q += accum[(size_t)s * 128 + 64 + c];
    }
    float mu = S / (float)M;
    float var = Q / (float)M - mu * mu;
    mu_istd[c] = mu;
    mu_istd[64 + c] = rsqrtf(var + EPSV);
}

// ---------------- BN apply + GEMM2 (64 -> 2) ----------------
__global__ __launch_bounds__(256) void bn_gemm2(const float* __restrict__ x,
                                                const float* __restrict__ mu_istd,
                                                const float* __restrict__ g,
                                                const float* __restrict__ bt,
                                                const float* __restrict__ W2,
                                                float* __restrict__ h2, int M) {
    int wid = (int)((blockIdx.x * (size_t)blockDim.x + threadIdx.x) >> 6);
    int c = threadIdx.x & 63;
    if (wid >= M) return;
    float v = x[(size_t)wid * 64 + c];
    v = (v - mu_istd[c]) * mu_istd[64 + c] * g[c] + bt[c];
    float p0 = v * W2[c * 2];
    float p1 = v * W2[c * 2 + 1];
    for (int off = 32; off; off >>= 1) {
        p0 += __shfl_down(p0, off);
        p1 += __shfl_down(p1, off);
    }
    if (c == 0) {
        float2 o = make_float2(p0, p1);
        *(float2*)&h2[(size_t)wid * 2] = o;
    }
}

// ---------------- gather agg2: thread per node ----------------
__global__ __launch_bounds__(256) void gather2(const int* __restrict__ rowptr,
                                               const int* __restrict__ adj,
                                               const float* __restrict__ dis,
                                               const float* __restrict__ h2,
                                               const float* __restrict__ b2,
                                               float* __restrict__ agg2, int n) {
    int node = blockIdx.x * 256 + threadIdx.x;
    if (node >= n) return;
    int beg = rowptr[node], end = rowptr[node + 1];
    float a0 = 0.f, a1 = 0.f;
    int j = beg;
    for (; j + 2 <= end; j += 2) {
        int s0 = adj[j], s1 = adj[j + 1];
        float d0 = dis[s0], d1 = dis[s1];
        float2 v0 = *(const float2*)&h2[(size_t)s0 * 2];
        float2 v1 = *(const float2*)&h2[(size_t)s1 * 2];
        a0 += d0 * v0.x + d1 * v1.x;
        a1 += d0 * v0.y + d1 * v1.y;
    }
    if (j < end) {
        int s0 = adj[j];
        float d0 = dis[s0];
        float2 v0 = *(const float2*)&h2[(size_t)s0 * 2];
        a0 += d0 * v0.x;
        a1 += d0 * v0.y;
    }
    float dn = dis[node];
    float sc = 2.f * dn * dn;
    float2 hv = *(const float2*)&h2[(size_t)node * 2];
    float2 o;
    o.x = dn * a0 + sc * hv.x + b2[0];
    o.y = dn * a1 + sc * hv.y + b2[1];
    *(float2*)&agg2[(size_t)node * 2] = o;
}

// ---------------- gating + mixture output ----------------
__global__ __launch_bounds__(256) void final_kernel(const float* __restrict__ moe,
                                                    const float* __restrict__ Wg,
                                                    const float* __restrict__ bg,
                                                    const float* __restrict__ agg2,  // [K][N][2]
                                                    float* __restrict__ out, int M) {
    int n = (int)((blockIdx.x * (size_t)blockDim.x + threadIdx.x) >> 6);
    int lane = threadIdx.x & 63;
    if (n >= M) return;
    float4 mf = *(const float4*)&moe[(size_t)n * 256 + lane * 4];
    const float* wr = &Wg[lane * 16];
    float a0 = mf.x * wr[0] + mf.y * wr[4] + mf.z * wr[8] + mf.w * wr[12];
    float a1 = mf.x * wr[1] + mf.y * wr[5] + mf.z * wr[9] + mf.w * wr[13];
    float a2 = mf.x * wr[2] + mf.y * wr[6] + mf.z * wr[10] + mf.w * wr[14];
    float a3 = mf.x * wr[3] + mf.y * wr[7] + mf.z * wr[11] + mf.w * wr[15];
    for (int mask = 1; mask < 64; mask <<= 1) {
        a0 += __shfl_xor(a0, mask);
        a1 += __shfl_xor(a1, mask);
        a2 += __shfl_xor(a2, mask);
        a3 += __shfl_xor(a3, mask);
    }
    if (lane == 0) {
        float gl[4] = {a0 + bg[0], a1 + bg[1], a2 + bg[2], a3 + bg[3]};
        float m = fmaxf(fmaxf(gl[0], gl[1]), fmaxf(gl[2], gl[3]));
        float w[4];
        float wsum = 0.f;
        for (int kk = 0; kk < 4; kk++) { w[kk] = expf(gl[kk] - m); wsum += w[kk]; }
        float o0 = 0.f, o1 = 0.f, q0 = 0.f, q1 = 0.f;
        for (int kk = 0; kk < 4; kk++) {
            float l0 = agg2[((size_t)kk * M + n) * 2];
            float l1 = agg2[((size_t)kk * M + n) * 2 + 1];
            float mm = fmaxf(l0, l1);
            float lse = mm + logf(expf(l0 - mm) + expf(l1 - mm));
            float lp0 = l0 - lse, lp1 = l1 - lse;
            float wk = w[kk] / wsum;
            o0 += wk * lp0; o1 += wk * lp1;
            q0 += wk * expf(lp0); q1 += wk * expf(lp1);
        }
        out[(size_t)n * 2] = o0;
        out[(size_t)n * 2 + 1] = o1;
        out[(size_t)2 * M + n * 2] = q0;
        out[(size_t)2 * M + n * 2 + 1] = q1;
    }
}

extern "C" void kernel_launch(void* const* d_in, const int* in_sizes, int n_in,
                              void* d_out, int out_size, void* d_ws, size_t ws_size,
                              hipStream_t stream) {
    const float* flatten = (const float*)d_in[0];
    const float* moe     = (const float*)d_in[1];
    const int*   edge    = (const int*)d_in[2];   // [K][2][E]
    const float* W1      = (const float*)d_in[3]; // [K][256][64]
    const float* b1      = (const float*)d_in[4]; // [K][64]
    const float* gamma   = (const float*)d_in[5];
    const float* beta    = (const float*)d_in[6];
    const float* W2      = (const float*)d_in[7]; // [K][64][2]
    const float* b2      = (const float*)d_in[8]; // [K][2]
    const float* Wg      = (const float*)d_in[9]; // [256][4]
    const float* bg      = (const float*)d_in[10];
    float* out = (float*)d_out;

    const int N = NN, E = EE, K = KEXP;

    char* ws = (char*)d_ws;
    size_t off = 0;
    auto alloc = [&](size_t bytes) -> void* {
        void* p = (void*)(ws + off);
        off += (bytes + 255) & ~(size_t)255;
        return p;
    };
    int*   rowptr  = (int*)alloc((size_t)K * (N + 1) * 4);
    float* dis     = (float*)alloc((size_t)K * N * 4);
    int*   bknt    = (int*)alloc((size_t)K * NBUCK * 4);
    int*   bbase   = (int*)alloc((size_t)K * (NBUCK + 1) * 4);
    int*   bcur    = (int*)alloc((size_t)K * NBUCK * 4);
    int*   adj     = (int*)alloc((size_t)K * E * 4);
    unsigned short* hbf = (unsigned short*)alloc((size_t)N * 64 * 2);
    float* x       = (float*)alloc((size_t)N * 64 * 4);
    float* h2      = (float*)alloc((size_t)N * 2 * 4);
    float* agg2    = (float*)alloc((size_t)K * N * 2 * 4);
    float* accum   = (float*)alloc((size_t)K * SLOTS * 128 * 4);
    float* mu_istd = (float*)alloc(128 * 4);
    (void)ws_size; (void)in_sizes; (void)n_in; (void)out_size;

    // bstream (K*E*4 = 25.6 MB) aliases hbf+x (12.8+25.6 MB contiguous):
    // only used in the build phase, before gemm1/gather1 write hbf/x.
    unsigned* bstream = (unsigned*)hbf;

    const int pgrid = (E + PCHUNK - 1) / PCHUNK;

    // ---- batched CSR build (bucket sort; all per-node work in LDS) ----
    hipMemsetAsync(bknt, 0, (size_t)K * NBUCK * 4, stream);
    hipMemsetAsync(accum, 0, (size_t)K * SLOTS * 128 * 4, stream);
    bucket_hist<<<dim3(pgrid, K), 256, 0, stream>>>(edge, bknt, E);
    bucket_scan<<<K, 256, 0, stream>>>(bknt, bbase, bcur, rowptr, N, E);
    partition_kernel<<<dim3(pgrid, K), 256, 0, stream>>>(edge, bcur, bstream, E);
    bucket_build<<<dim3(NBUCK, K), 256, 0, stream>>>(bbase, bstream, rowptr, dis, adj, N, E);

    // ---- per-expert pipeline ----
    for (int k = 0; k < K; k++) {
        const int* rp = rowptr + (size_t)k * (N + 1);
        const int* aj = adj + (size_t)k * E;
        const float* dk = dis + (size_t)k * N;
        float* ak = accum + (size_t)k * SLOTS * 128;
        gemm1_kernel<<<(N + 63) / 64, 256, 0, stream>>>(
            flatten, W1 + (size_t)k * 256 * 64, hbf, N);
        gather1<<<(N + 3) / 4, 256, 0, stream>>>(
            rp, aj, dk, hbf, b1 + (size_t)k * 64, x, ak, N);
        stats_fin<<<1, 64, 0, stream>>>(ak, mu_istd, N);
        bn_gemm2<<<(int)(((size_t)N * 64 + 255) / 256), 256, 0, stream>>>(
            x, mu_istd, gamma + (size_t)k * 64, beta + (size_t)k * 64,
            W2 + (size_t)k * 128, h2, N);
        gather2<<<(N + 255) / 256, 256, 0, stream>>>(
            rp, aj, dk, h2, b2 + (size_t)k * 2, agg2 + (size_t)k * N * 2, N);
    }
    final_kernel<<<(int)(((size_t)N * 64 + 255) / 256), 256, 0, stream>>>(
        moe, Wg, bg, agg2, out, N);
}

// Round 7
// 1002.874 us; speedup vs baseline: 4.2454x; 1.1036x over previous
//
#include <hip/hip_runtime.h>
#include <math.h>

#define NN 100000
#define KEXP 4
#define EE 1600000
#define EPSV 1e-5f
#define BSHIFT 9
#define BSIZE 512
#define NBUCK 196       // ceil(100000/512)
#define PCHUNK 4096     // edges per block in hist/partition kernels
#define PG ((EE + PCHUNK - 1) / PCHUNK)   // 391
#define SLOTS 64        // hashed stat accumulator slots

typedef __attribute__((ext_vector_type(8))) short bfrag8;
typedef __attribute__((ext_vector_type(16))) float facc16;

__device__ __forceinline__ unsigned short f2bf(float f) {
    unsigned u = __float_as_uint(f);
    return (unsigned short)((u + 0x7fff + ((u >> 16) & 1)) >> 16);
}
__device__ __forceinline__ float bf_lo(unsigned u) { return __uint_as_float(u << 16); }
__device__ __forceinline__ float bf_hi(unsigned u) { return __uint_as_float(u & 0xffff0000u); }

// ---------------- radix pass 1: per-(block,bucket) histogram, no atomics --
__global__ __launch_bounds__(256) void hist_pass(const int* __restrict__ edge,
                                                 int* __restrict__ blockhist, int E) {
    int k = blockIdx.y, bx = blockIdx.x;
    const int* dp = edge + (size_t)k * 2 * E + E;
    __shared__ int hist[NBUCK];
    for (int i = threadIdx.x; i < NBUCK; i += 256) hist[i] = 0;
    __syncthreads();
    int cb = bx * PCHUNK, ce = cb + PCHUNK;
    if (ce > E) ce = E;
    for (int e = cb + (int)threadIdx.x; e < ce; e += 256)
        atomicAdd(&hist[dp[e] >> BSHIFT], 1);
    __syncthreads();
    for (int i = threadIdx.x; i < NBUCK; i += 256)
        blockhist[((size_t)k * PG + bx) * NBUCK + i] = hist[i];
}

// ---------------- radix pass 2: column scan -> per-block bases + bucket
// bases (blockhist overwritten in place with exclusive per-block prefix) ----
__global__ __launch_bounds__(256) void scan_pass(int* __restrict__ blockhist,
                                                 int* __restrict__ bbase,
                                                 int* __restrict__ rowptr,
                                                 int n, int E) {
    int k = blockIdx.x;
    int t = threadIdx.x;
    int running = 0;
    if (t < NBUCK) {
        for (int j = 0; j < PG; j++) {
            size_t idx = ((size_t)k * PG + j) * NBUCK + t;
            int v = blockhist[idx];
            blockhist[idx] = running;
            running += v;
        }
    }
    __shared__ int sd[256];
    sd[t] = (t < NBUCK) ? running : 0;
    __syncthreads();
    for (int o = 1; o < 256; o <<= 1) {
        int x = (t >= o) ? sd[t - o] : 0;
        __syncthreads();
        sd[t] += x;
        __syncthreads();
    }
    if (t < NBUCK) bbase[k * (NBUCK + 1) + t] = sd[t] - running;
    if (t == 0) {
        bbase[k * (NBUCK + 1) + NBUCK] = E;
        rowptr[(size_t)k * (n + 1) + n] = E;
    }
}

// ---------------- radix pass 3: scatter into bucket streams, LDS cursors,
// zero global atomics.  pack = (d&511)<<17 | s  (s < 2^17) ----------------
__global__ __launch_bounds__(256) void partition_pass(const int* __restrict__ edge,
                                                      const int* __restrict__ blockhist,
                                                      const int* __restrict__ bbase,
                                                      unsigned* __restrict__ bstream,
                                                      int E) {
    int k = blockIdx.y, bx = blockIdx.x;
    __shared__ int cur[NBUCK];
    for (int i = threadIdx.x; i < NBUCK; i += 256)
        cur[i] = bbase[k * (NBUCK + 1) + i] + blockhist[((size_t)k * PG + bx) * NBUCK + i];
    __syncthreads();
    const int* sp = edge + (size_t)k * 2 * E;
    const int* dp = sp + E;
    int cb = bx * PCHUNK, ce = cb + PCHUNK;
    if (ce > E) ce = E;
    unsigned* bs = bstream + (size_t)k * E;
    for (int e = cb + (int)threadIdx.x; e < ce; e += 256) {
        int s = sp[e];
        int d = dp[e];
        int pos = atomicAdd(&cur[d >> BSHIFT], 1);
        bs[pos] = ((unsigned)(d & (BSIZE - 1)) << 17) | (unsigned)s;
    }
}

// ---------------- per-bucket: degree hist + scan + rowptr + dis + scatter --
__global__ __launch_bounds__(256) void bucket_build(const int* __restrict__ bbase,
                                                    const unsigned* __restrict__ bstream,
                                                    int* __restrict__ rowptr,
                                                    float* __restrict__ dis,
                                                    int* __restrict__ adj,
                                                    int n, int E) {
    int k = blockIdx.y;
    int b = blockIdx.x;
    int nb = b << BSHIFT;
    int t = threadIdx.x;
    __shared__ int hist[BSIZE];
    __shared__ int curx[BSIZE];
    __shared__ int tmp[256];
    hist[t] = 0;
    hist[t + 256] = 0;
    __syncthreads();
    int beg = bbase[k * (NBUCK + 1) + b];
    int end = bbase[k * (NBUCK + 1) + b + 1];
    const unsigned* bs = bstream + (size_t)k * E;
    for (int p = beg + t; p < end; p += 256) {
        atomicAdd(&hist[bs[p] >> 17], 1);
    }
    __syncthreads();
    int a0 = hist[2 * t], a1 = hist[2 * t + 1];
    tmp[t] = a0 + a1;
    __syncthreads();
    for (int o = 1; o < 256; o <<= 1) {
        int x = (t >= o) ? tmp[t - o] : 0;
        __syncthreads();
        tmp[t] += x;
        __syncthreads();
    }
    int ex = tmp[t] - (a0 + a1);  // exclusive prefix over pairs
    int c0 = beg + ex;
    int c1 = c0 + a0;
    curx[2 * t] = c0;
    curx[2 * t + 1] = c1;
    int* rp = rowptr + (size_t)k * (n + 1);
    float* dk = dis + (size_t)k * n;
    int node0 = nb + 2 * t, node1 = nb + 2 * t + 1;
    if (node0 < n) { rp[node0] = c0; dk[node0] = rsqrtf((float)a0 + 2.0f); }
    if (node1 < n) { rp[node1] = c1; dk[node1] = rsqrtf((float)a1 + 2.0f); }
    __syncthreads();
    int* aj = adj + (size_t)k * E;
    for (int p = beg + t; p < end; p += 256) {
        unsigned pk = bs[p];
        int pos = atomicAdd(&curx[pk >> 17], 1);
        aj[pos] = (int)(pk & 0x1FFFFu);
    }
}

// ---------------- convert flatten -> bf16 (once) ----------------
__global__ __launch_bounds__(256) void a2bf_kernel(const float* __restrict__ A,
                                                   unsigned short* __restrict__ abf,
                                                   int n4) {
    int i = blockIdx.x * 256 + threadIdx.x;
    if (i >= n4) return;
    float4 v = ((const float4*)A)[i];
    ushort4 o;
    o.x = f2bf(v.x); o.y = f2bf(v.y); o.z = f2bf(v.z); o.w = f2bf(v.w);
    ((ushort4*)abf)[i] = o;
}

// ---------------- convert + transpose W1 -> Wt[k][col][kk] bf16 ----------
__global__ __launch_bounds__(256) void w2bf_kernel(const float* __restrict__ W1,
                                                   unsigned short* __restrict__ Wt) {
    int k = blockIdx.x;
    for (int idx = threadIdx.x; idx < 64 * 256; idx += 256) {
        int c = idx >> 8;       // col 0..63
        int kk = idx & 255;     // k 0..255
        Wt[(size_t)k * 64 * 256 + c * 256 + kk] = f2bf(W1[(size_t)k * 256 * 64 + kk * 64 + c]);
    }
}

// ---------------- GEMM1 (MFMA): h = A @ W (M x 256 x 64), bf16 in/out ----
__global__ __launch_bounds__(256) void gemm1_mfma(
    const unsigned short* __restrict__ abf,  // [M,256] bf16
    const unsigned short* __restrict__ Wt,   // [64,256] bf16 (W^T)
    unsigned short* __restrict__ hbf,        // [M,64] bf16
    int M) {
    __shared__ __align__(16) unsigned short As[64][72];  // [row][k], +8 pad
    __shared__ __align__(16) unsigned short Bs[64][72];  // [col][k]
    int t = threadIdx.x;
    int row0 = blockIdx.x * 64;
    int wid = t >> 6, lane = t & 63;
    int qr = wid >> 1, qc = wid & 1;
    facc16 acc;
    for (int i = 0; i < 16; i++) acc[i] = 0.f;

    for (int kc = 0; kc < 256; kc += 64) {
        for (int i = 0; i < 2; i++) {
            int fid = t + i * 256;    // 0..511
            int r = fid >> 3;
            int o = (fid & 7) * 8;
            int row = row0 + r;
            uint4 v = make_uint4(0u, 0u, 0u, 0u);
            if (row < M) v = *(const uint4*)&abf[(size_t)row * 256 + kc + o];
            *(uint4*)&As[r][o] = v;
        }
        for (int i = 0; i < 2; i++) {
            int fid = t + i * 256;
            int c = fid >> 3;
            int o = (fid & 7) * 8;
            uint4 v = *(const uint4*)&Wt[(size_t)c * 256 + kc + o];
            *(uint4*)&Bs[c][o] = v;
        }
        __syncthreads();
        int arow = qr * 32 + (lane & 31);
        int bcol = qc * 32 + (lane & 31);
        int ko = (lane >> 5) * 8;
        for (int kk = 0; kk < 64; kk += 16) {
            bfrag8 a = *(const bfrag8*)&As[arow][kk + ko];
            bfrag8 b = *(const bfrag8*)&Bs[bcol][kk + ko];
            acc = __builtin_amdgcn_mfma_f32_32x32x16_bf16(a, b, acc, 0, 0, 0);
        }
        __syncthreads();
    }
    int col = qc * 32 + (lane & 31);
    for (int i = 0; i < 16; i++) {
        int rl = (i & 3) + 8 * (i >> 2) + 4 * (lane >> 5);
        int row = row0 + qr * 32 + rl;
        if (row < M) hbf[(size_t)row * 64 + col] = f2bf(acc[i]);
    }
}

// ---------------- GEMM1 fallback (fp32 VALU), bf16 out ----------------
__global__ __launch_bounds__(256) void gemm1_fp32(
    const float* __restrict__ A, const float* __restrict__ W,
    unsigned short* __restrict__ hbf, int M) {
    __shared__ __align__(16) float As[64][65];
    __shared__ __align__(16) float Ws[64][68];
    int t = threadIdx.x;
    int row0 = blockIdx.x * 64;
    int tr = t >> 4;
    int tc = t & 15;
    float acc[4][4] = {{0.f}};
    for (int kc = 0; kc < 256; kc += 64) {
        for (int i = 0; i < 4; i++) {
            int fid = t + i * 256;
            int r = fid >> 4;
            int c4 = (fid & 15) << 2;
            int row = row0 + r;
            float4 v = make_float4(0.f, 0.f, 0.f, 0.f);
            if (row < M) v = *(const float4*)&A[(size_t)row * 256 + kc + c4];
            As[r][c4] = v.x; As[r][c4 + 1] = v.y; As[r][c4 + 2] = v.z; As[r][c4 + 3] = v.w;
        }
        for (int i = 0; i < 4; i++) {
            int fid = t + i * 256;
            int r = fid >> 4;
            int c4 = (fid & 15) << 2;
            float4 v = *(const float4*)&W[(size_t)(kc + r) * 64 + c4];
            *(float4*)&Ws[r][c4] = v;
        }
        __syncthreads();
        for (int kk = 0; kk < 64; kk++) {
            float a0 = As[tr * 4 + 0][kk];
            float a1 = As[tr * 4 + 1][kk];
            float a2 = As[tr * 4 + 2][kk];
            float a3 = As[tr * 4 + 3][kk];
            float4 w = *(const float4*)&Ws[kk][tc * 4];
            acc[0][0] += a0 * w.x; acc[0][1] += a0 * w.y; acc[0][2] += a0 * w.z; acc[0][3] += a0 * w.w;
            acc[1][0] += a1 * w.x; acc[1][1] += a1 * w.y; acc[1][2] += a1 * w.z; acc[1][3] += a1 * w.w;
            acc[2][0] += a2 * w.x; acc[2][1] += a2 * w.y; acc[2][2] += a2 * w.z; acc[2][3] += a2 * w.w;
            acc[3][0] += a3 * w.x; acc[3][1] += a3 * w.y; acc[3][2] += a3 * w.z; acc[3][3] += a3 * w.w;
        }
        __syncthreads();
    }
    for (int i = 0; i < 4; i++) {
        int row = row0 + tr * 4 + i;
        if (row >= M) continue;
        ushort4 o;
        o.x = f2bf(acc[i][0]); o.y = f2bf(acc[i][1]);
        o.z = f2bf(acc[i][2]); o.w = f2bf(acc[i][3]);
        *(ushort4*)&hbf[(size_t)row * 64 + 4 * tc] = o;
    }
}

// ---------------- gather agg1: wave per node, 2 edges/iter (lane halves),
// bf16 h, fused relu + BN stats (hashed-slot global accumulate) ----------
__global__ __launch_bounds__(256) void gather1(const int* __restrict__ rowptr,
                                               const int* __restrict__ adj,
                                               const float* __restrict__ dis,
                                               const unsigned short* __restrict__ hbf,
                                               const float* __restrict__ b1,
                                               float* __restrict__ x,
                                               float* __restrict__ accum, int n) {
    __shared__ float ls[4][64];
    __shared__ float lq[4][64];
    ((float*)ls)[threadIdx.x] = 0.f;
    ((float*)lq)[threadIdx.x] = 0.f;
    __syncthreads();
    int w = threadIdx.x >> 6;
    int node = blockIdx.x * 4 + w;
    int lane = threadIdx.x & 63;
    int half = lane >> 5;
    int p = lane & 31;
    if (node < n) {
        int beg = rowptr[node], end = rowptr[node + 1];
        float ax = 0.f, ay = 0.f;
        int j = beg + half;
        for (; j + 2 < end; j += 4) {
            int s0 = adj[j], s1 = adj[j + 2];
            float d0 = dis[s0], d1 = dis[s1];
            unsigned u0 = *(const unsigned*)&hbf[(size_t)s0 * 64 + 2 * p];
            unsigned u1 = *(const unsigned*)&hbf[(size_t)s1 * 64 + 2 * p];
            ax += d0 * bf_lo(u0) + d1 * bf_lo(u1);
            ay += d0 * bf_hi(u0) + d1 * bf_hi(u1);
        }
        if (j < end) {
            int s0 = adj[j];
            float d0 = dis[s0];
            unsigned u0 = *(const unsigned*)&hbf[(size_t)s0 * 64 + 2 * p];
            ax += d0 * bf_lo(u0);
            ay += d0 * bf_hi(u0);
        }
        ax += __shfl_xor(ax, 32);
        ay += __shfl_xor(ay, 32);
        float dn = dis[node];
        float sc = 2.f * dn * dn;
        unsigned us = *(const unsigned*)&hbf[(size_t)node * 64 + 2 * p];
        float vx = dn * ax + sc * bf_lo(us) + b1[2 * p];
        float vy = dn * ay + sc * bf_hi(us) + b1[2 * p + 1];
        vx = fmaxf(vx, 0.f);
        vy = fmaxf(vy, 0.f);
        if (half == 0) {
            *(float2*)&x[(size_t)node * 64 + 2 * p] = make_float2(vx, vy);
            ls[w][2 * p] = vx;
            ls[w][2 * p + 1] = vy;
            lq[w][2 * p] = vx * vx;
            lq[w][2 * p + 1] = vy * vy;
        }
    }
    __syncthreads();
    if (threadIdx.x < 64) {
        int c = threadIdx.x;
        float S = ls[0][c] + ls[1][c] + ls[2][c] + ls[3][c];
        float Q = lq[0][c] + lq[1][c] + lq[2][c] + lq[3][c];
        float* slot = accum + (size_t)(blockIdx.x & (SLOTS - 1)) * 128;
        unsafeAtomicAdd(&slot[c], S);
        unsafeAtomicAdd(&slot[64 + c], Q);
    }
}

__global__ void stats_fin(const float* __restrict__ accum,
                          float* __restrict__ mu_istd, int M) {
    int c = threadIdx.x;  // 64 threads
    float S = 0.f, Q = 0.f;
    for (int s = 0; s < SLOTS; s++) {
        S += accum[(size_t)s * 128 + c];
        Q += accum[(size_t)s * 128 + 64 + c];
    }
    float mu = S / (float)M;
    float var = Q / (float)M - mu * mu;
    mu_istd[c] = mu;
    mu_istd[64 + c] = rsqrtf(var + EPSV);
}

// ---------------- BN apply + GEMM2 (64 -> 2) ----------------
__global__ __launch_bounds__(256) void bn_gemm2(const float* __restrict__ x,
                                                const float* __restrict__ mu_istd,
                                                const float* __restrict__ g,
                                                const float* __restrict__ bt,
                                                const float* __restrict__ W2,
                                                float* __restrict__ h2, int M) {
    int wid = (int)((blockIdx.x * (size_t)blockDim.x + threadIdx.x) >> 6);
    int c = threadIdx.x & 63;
    if (wid >= M) return;
    float v = x[(size_t)wid * 64 + c];
    v = (v - mu_istd[c]) * mu_istd[64 + c] * g[c] + bt[c];
    float p0 = v * W2[c * 2];
    float p1 = v * W2[c * 2 + 1];
    for (int off = 32; off; off >>= 1) {
        p0 += __shfl_down(p0, off);
        p1 += __shfl_down(p1, off);
    }
    if (c == 0) {
        float2 o = make_float2(p0, p1);
        *(float2*)&h2[(size_t)wid * 2] = o;
    }
}

// ---------------- gather agg2: thread per node ----------------
__global__ __launch_bounds__(256) void gather2(const int* __restrict__ rowptr,
                                               const int* __restrict__ adj,
                                               const float* __restrict__ dis,
                                               const float* __restrict__ h2,
                                               const float* __restrict__ b2,
                                               float* __restrict__ agg2, int n) {
    int node = blockIdx.x * 256 + threadIdx.x;
    if (node >= n) return;
    int beg = rowptr[node], end = rowptr[node + 1];
    float a0 = 0.f, a1 = 0.f;
    int j = beg;
    for (; j + 2 <= end; j += 2) {
        int s0 = adj[j], s1 = adj[j + 1];
        float d0 = dis[s0], d1 = dis[s1];
        float2 v0 = *(const float2*)&h2[(size_t)s0 * 2];
        float2 v1 = *(const float2*)&h2[(size_t)s1 * 2];
        a0 += d0 * v0.x + d1 * v1.x;
        a1 += d0 * v0.y + d1 * v1.y;
    }
    if (j < end) {
        int s0 = adj[j];
        float d0 = dis[s0];
        float2 v0 = *(const float2*)&h2[(size_t)s0 * 2];
        a0 += d0 * v0.x;
        a1 += d0 * v0.y;
    }
    float dn = dis[node];
    float sc = 2.f * dn * dn;
    float2 hv = *(const float2*)&h2[(size_t)node * 2];
    float2 o;
    o.x = dn * a0 + sc * hv.x + b2[0];
    o.y = dn * a1 + sc * hv.y + b2[1];
    *(float2*)&agg2[(size_t)node * 2] = o;
}

// ---------------- gating + mixture output ----------------
__global__ __launch_bounds__(256) void final_kernel(const float* __restrict__ moe,
                                                    const float* __restrict__ Wg,
                                                    const float* __restrict__ bg,
                                                    const float* __restrict__ agg2,  // [K][N][2]
                                                    float* __restrict__ out, int M) {
    int n = (int)((blockIdx.x * (size_t)blockDim.x + threadIdx.x) >> 6);
    int lane = threadIdx.x & 63;
    if (n >= M) return;
    float4 mf = *(const float4*)&moe[(size_t)n * 256 + lane * 4];
    const float* wr = &Wg[lane * 16];
    float a0 = mf.x * wr[0] + mf.y * wr[4] + mf.z * wr[8] + mf.w * wr[12];
    float a1 = mf.x * wr[1] + mf.y * wr[5] + mf.z * wr[9] + mf.w * wr[13];
    float a2 = mf.x * wr[2] + mf.y * wr[6] + mf.z * wr[10] + mf.w * wr[14];
    float a3 = mf.x * wr[3] + mf.y * wr[7] + mf.z * wr[11] + mf.w * wr[15];
    for (int mask = 1; mask < 64; mask <<= 1) {
        a0 += __shfl_xor(a0, mask);
        a1 += __shfl_xor(a1, mask);
        a2 += __shfl_xor(a2, mask);
        a3 += __shfl_xor(a3, mask);
    }
    if (lane == 0) {
        float gl[4] = {a0 + bg[0], a1 + bg[1], a2 + bg[2], a3 + bg[3]};
        float m = fmaxf(fmaxf(gl[0], gl[1]), fmaxf(gl[2], gl[3]));
        float w[4];
        float wsum = 0.f;
        for (int kk = 0; kk < 4; kk++) { w[kk] = expf(gl[kk] - m); wsum += w[kk]; }
        float o0 = 0.f, o1 = 0.f, q0 = 0.f, q1 = 0.f;
        for (int kk = 0; kk < 4; kk++) {
            float l0 = agg2[((size_t)kk * M + n) * 2];
            float l1 = agg2[((size_t)kk * M + n) * 2 + 1];
            float mm = fmaxf(l0, l1);
            float lse = mm + logf(expf(l0 - mm) + expf(l1 - mm));
            float lp0 = l0 - lse, lp1 = l1 - lse;
            float wk = w[kk] / wsum;
            o0 += wk * lp0; o1 += wk * lp1;
            q0 += wk * expf(lp0); q1 += wk * expf(lp1);
        }
        out[(size_t)n * 2] = o0;
        out[(size_t)n * 2 + 1] = o1;
        out[(size_t)2 * M + n * 2] = q0;
        out[(size_t)2 * M + n * 2 + 1] = q1;
    }
}

extern "C" void kernel_launch(void* const* d_in, const int* in_sizes, int n_in,
                              void* d_out, int out_size, void* d_ws, size_t ws_size,
                              hipStream_t stream) {
    const float* flatten = (const float*)d_in[0];
    const float* moe     = (const float*)d_in[1];
    const int*   edge    = (const int*)d_in[2];   // [K][2][E]
    const float* W1      = (const float*)d_in[3]; // [K][256][64]
    const float* b1      = (const float*)d_in[4]; // [K][64]
    const float* gamma   = (const float*)d_in[5];
    const float* beta    = (const float*)d_in[6];
    const float* W2      = (const float*)d_in[7]; // [K][64][2]
    const float* b2      = (const float*)d_in[8]; // [K][2]
    const float* Wg      = (const float*)d_in[9]; // [256][4]
    const float* bg      = (const float*)d_in[10];
    float* out = (float*)d_out;

    const int N = NN, E = EE, K = KEXP;

    char* ws = (char*)d_ws;
    size_t off = 0;
    auto alloc = [&](size_t bytes) -> void* {
        void* p = (void*)(ws + off);
        off += (bytes + 255) & ~(size_t)255;
        return p;
    };
    int*   rowptr    = (int*)alloc((size_t)K * (N + 1) * 4);
    float* dis       = (float*)alloc((size_t)K * N * 4);
    int*   blockhist = (int*)alloc((size_t)K * PG * NBUCK * 4);
    int*   bbase     = (int*)alloc((size_t)K * (NBUCK + 1) * 4);
    int*   adj       = (int*)alloc((size_t)K * E * 4);
    unsigned short* hbf = (unsigned short*)alloc((size_t)N * 64 * 2);
    float* x         = (float*)alloc((size_t)N * 64 * 4);
    float* h2        = (float*)alloc((size_t)N * 2 * 4);
    float* agg2      = (float*)alloc((size_t)K * N * 2 * 4);
    float* accum     = (float*)alloc((size_t)K * SLOTS * 128 * 4);
    float* mu_istd   = (float*)alloc(128 * 4);
    size_t base_need = off;
    unsigned short* abf = (unsigned short*)alloc((size_t)N * 256 * 2);
    unsigned short* Wt  = (unsigned short*)alloc((size_t)K * 64 * 256 * 2);
    size_t mfma_need = off;
    (void)in_sizes; (void)n_in; (void)out_size; (void)base_need;
    bool use_mfma = (ws_size >= mfma_need);

    // bstream (K*E*4 = 25.6 MB) aliases hbf+x (12.8+25.6 MB contiguous):
    // only used in the build phase, before gemm1/gather1 write hbf/x.
    unsigned* bstream = (unsigned*)hbf;

    // ---- batched CSR build: atomic-free 3-pass bucket radix sort ----
    hipMemsetAsync(accum, 0, (size_t)K * SLOTS * 128 * 4, stream);
    hist_pass<<<dim3(PG, K), 256, 0, stream>>>(edge, blockhist, E);
    scan_pass<<<K, 256, 0, stream>>>(blockhist, bbase, rowptr, N, E);
    partition_pass<<<dim3(PG, K), 256, 0, stream>>>(edge, blockhist, bbase, bstream, E);
    bucket_build<<<dim3(NBUCK, K), 256, 0, stream>>>(bbase, bstream, rowptr, dis, adj, N, E);

    if (use_mfma) {
        a2bf_kernel<<<(N * 256 / 4 + 255) / 256, 256, 0, stream>>>(flatten, abf, N * 256 / 4);
        w2bf_kernel<<<K, 256, 0, stream>>>(W1, Wt);
    }

    // ---- per-expert pipeline ----
    for (int k = 0; k < K; k++) {
        const int* rp = rowptr + (size_t)k * (N + 1);
        const int* aj = adj + (size_t)k * E;
        const float* dk = dis + (size_t)k * N;
        float* ak = accum + (size_t)k * SLOTS * 128;
        if (use_mfma) {
            gemm1_mfma<<<(N + 63) / 64, 256, 0, stream>>>(
                abf, Wt + (size_t)k * 64 * 256, hbf, N);
        } else {
            gemm1_fp32<<<(N + 63) / 64, 256, 0, stream>>>(
                flatten, W1 + (size_t)k * 256 * 64, hbf, N);
        }
        gather1<<<(N + 3) / 4, 256, 0, stream>>>(
            rp, aj, dk, hbf, b1 + (size_t)k * 64, x, ak, N);
        stats_fin<<<1, 64, 0, stream>>>(ak, mu_istd, N);
        bn_gemm2<<<(int)(((size_t)N * 64 + 255) / 256), 256, 0, stream>>>(
            x, mu_istd, gamma + (size_t)k * 64, beta + (size_t)k * 64,
            W2 + (size_t)k * 128, h2, N);
        gather2<<<(N + 255) / 256, 256, 0, stream>>>(
            rp, aj, dk, h2, b2 + (size_t)k * 2, agg2 + (size_t)k * N * 2, N);
    }
    final_kernel<<<(int)(((size_t)N * 64 + 255) / 256), 256, 0, stream>>>(
        moe, Wg, bg, agg2, out, N);
}

// Round 8
// 949.362 us; speedup vs baseline: 4.4846x; 1.0564x over previous
//
#include <hip/hip_runtime.h>
#include <math.h>

#define NN 100000
#define KEXP 4
#define EE 1600000
#define EPSV 1e-5f
#define BSHIFT 9
#define BSIZE 512
#define NBUCK 196       // ceil(100000/512)
#define PCHUNK 4096     // edges per block in hist/partition kernels
#define PG ((EE + PCHUNK - 1) / PCHUNK)   // 391
#define SLOTS 64        // hashed stat accumulator slots

typedef __attribute__((ext_vector_type(8))) short bfrag8;
typedef __attribute__((ext_vector_type(16))) float facc16;

__device__ __forceinline__ unsigned short f2bf(float f) {
    unsigned u = __float_as_uint(f);
    return (unsigned short)((u + 0x7fff + ((u >> 16) & 1)) >> 16);
}
__device__ __forceinline__ float bf_lo(unsigned u) { return __uint_as_float(u << 16); }
__device__ __forceinline__ float bf_hi(unsigned u) { return __uint_as_float(u & 0xffff0000u); }

// ---------------- radix pass 1: per-(block,bucket) histogram, no atomics --
__global__ __launch_bounds__(256) void hist_pass(const int* __restrict__ edge,
                                                 int* __restrict__ blockhist, int E) {
    int k = blockIdx.y, bx = blockIdx.x;
    const int* dp = edge + (size_t)k * 2 * E + E;
    __shared__ int hist[NBUCK];
    for (int i = threadIdx.x; i < NBUCK; i += 256) hist[i] = 0;
    __syncthreads();
    int cb = bx * PCHUNK, ce = cb + PCHUNK;
    if (ce > E) ce = E;
    for (int e = cb + (int)threadIdx.x; e < ce; e += 256)
        atomicAdd(&hist[dp[e] >> BSHIFT], 1);
    __syncthreads();
    for (int i = threadIdx.x; i < NBUCK; i += 256)
        blockhist[((size_t)k * PG + bx) * NBUCK + i] = hist[i];
}

// ---------------- radix pass 2: column scan -> per-block bases + bucket
// bases (blockhist overwritten in place with exclusive per-block prefix) ----
__global__ __launch_bounds__(256) void scan_pass(int* __restrict__ blockhist,
                                                 int* __restrict__ bbase,
                                                 int* __restrict__ rowptr,
                                                 int n, int E) {
    int k = blockIdx.x;
    int t = threadIdx.x;
    int running = 0;
    if (t < NBUCK) {
        for (int j = 0; j < PG; j++) {
            size_t idx = ((size_t)k * PG + j) * NBUCK + t;
            int v = blockhist[idx];
            blockhist[idx] = running;
            running += v;
        }
    }
    __shared__ int sd[256];
    sd[t] = (t < NBUCK) ? running : 0;
    __syncthreads();
    for (int o = 1; o < 256; o <<= 1) {
        int x = (t >= o) ? sd[t - o] : 0;
        __syncthreads();
        sd[t] += x;
        __syncthreads();
    }
    if (t < NBUCK) bbase[k * (NBUCK + 1) + t] = sd[t] - running;
    if (t == 0) {
        bbase[k * (NBUCK + 1) + NBUCK] = E;
        rowptr[(size_t)k * (n + 1) + n] = E;
    }
}

// ---------------- radix pass 3: LDS-staged local sort + coalesced dump ----
// pack = (d&511)<<17 | s  (s < 2^17).  The chunk is fully bucket-sorted in
// LDS first; the dump writes dense runs (consecutive lanes -> consecutive
// global addresses), collapsing the scattered-4B-store transaction storm.
__global__ __launch_bounds__(256) void partition_pass(const int* __restrict__ edge,
                                                      const int* __restrict__ blockhist,
                                                      const int* __restrict__ bbase,
                                                      unsigned* __restrict__ bstream,
                                                      int E) {
    int k = blockIdx.y, bx = blockIdx.x;
    int t = threadIdx.x;
    __shared__ int hist[NBUCK];        // counts -> cursors
    __shared__ int lofs[NBUCK + 1];    // local exclusive prefix
    __shared__ int gbase[NBUCK];       // global dest base for this block
    __shared__ int tmp[256];
    __shared__ unsigned stage[PCHUNK]; // 16 KB
    for (int i = t; i < NBUCK; i += 256) {
        hist[i] = 0;
        gbase[i] = bbase[k * (NBUCK + 1) + i] + blockhist[((size_t)k * PG + bx) * NBUCK + i];
    }
    __syncthreads();
    const int* sp = edge + (size_t)k * 2 * E;
    const int* dp = sp + E;
    int cb = bx * PCHUNK, ce = cb + PCHUNK;
    if (ce > E) ce = E;
    int cnt = ce - cb;
    for (int e = cb + t; e < ce; e += 256)
        atomicAdd(&hist[dp[e] >> BSHIFT], 1);
    __syncthreads();
    int v = (t < NBUCK) ? hist[t] : 0;
    tmp[t] = v;
    __syncthreads();
    for (int o = 1; o < 256; o <<= 1) {
        int x = (t >= o) ? tmp[t - o] : 0;
        __syncthreads();
        tmp[t] += x;
        __syncthreads();
    }
    if (t < NBUCK) { lofs[t] = tmp[t] - v; hist[t] = tmp[t] - v; }
    if (t == 0) lofs[NBUCK] = cnt;
    __syncthreads();
    for (int e = cb + t; e < ce; e += 256) {
        int s = sp[e];
        int d = dp[e];
        int r = atomicAdd(&hist[d >> BSHIFT], 1);
        stage[r] = ((unsigned)(d & (BSIZE - 1)) << 17) | (unsigned)s;
    }
    __syncthreads();
    unsigned* bs = bstream + (size_t)k * E;
    for (int i = t; i < cnt; i += 256) {
        int lo = 0, hi = NBUCK;
        while (hi - lo > 1) {
            int mid = (lo + hi) >> 1;
            if (lofs[mid] <= i) lo = mid; else hi = mid;
        }
        bs[gbase[lo] + (i - lofs[lo])] = stage[i];
    }
}

// ---------------- per-bucket: degree hist + scan + rowptr + dis + scatter --
__global__ __launch_bounds__(256) void bucket_build(const int* __restrict__ bbase,
                                                    const unsigned* __restrict__ bstream,
                                                    int* __restrict__ rowptr,
                                                    float* __restrict__ dis,
                                                    int* __restrict__ adj,
                                                    int n, int E) {
    int k = blockIdx.y;
    int b = blockIdx.x;
    int nb = b << BSHIFT;
    int t = threadIdx.x;
    __shared__ int hist[BSIZE];
    __shared__ int curx[BSIZE];
    __shared__ int tmp[256];
    hist[t] = 0;
    hist[t + 256] = 0;
    __syncthreads();
    int beg = bbase[k * (NBUCK + 1) + b];
    int end = bbase[k * (NBUCK + 1) + b + 1];
    const unsigned* bs = bstream + (size_t)k * E;
    for (int p = beg + t; p < end; p += 256) {
        atomicAdd(&hist[bs[p] >> 17], 1);
    }
    __syncthreads();
    int a0 = hist[2 * t], a1 = hist[2 * t + 1];
    tmp[t] = a0 + a1;
    __syncthreads();
    for (int o = 1; o < 256; o <<= 1) {
        int x = (t >= o) ? tmp[t - o] : 0;
        __syncthreads();
        tmp[t] += x;
        __syncthreads();
    }
    int ex = tmp[t] - (a0 + a1);  // exclusive prefix over pairs
    int c0 = beg + ex;
    int c1 = c0 + a0;
    curx[2 * t] = c0;
    curx[2 * t + 1] = c1;
    int* rp = rowptr + (size_t)k * (n + 1);
    float* dk = dis + (size_t)k * n;
    int node0 = nb + 2 * t, node1 = nb + 2 * t + 1;
    if (node0 < n) { rp[node0] = c0; dk[node0] = rsqrtf((float)a0 + 2.0f); }
    if (node1 < n) { rp[node1] = c1; dk[node1] = rsqrtf((float)a1 + 2.0f); }
    __syncthreads();
    int* aj = adj + (size_t)k * E;
    for (int p = beg + t; p < end; p += 256) {
        unsigned pk = bs[p];
        int pos = atomicAdd(&curx[pk >> 17], 1);
        aj[pos] = (int)(pk & 0x1FFFFu);
    }
}

// ---------------- convert flatten -> bf16 (once) ----------------
__global__ __launch_bounds__(256) void a2bf_kernel(const float* __restrict__ A,
                                                   unsigned short* __restrict__ abf,
                                                   int n4) {
    int i = blockIdx.x * 256 + threadIdx.x;
    if (i >= n4) return;
    float4 v = ((const float4*)A)[i];
    ushort4 o;
    o.x = f2bf(v.x); o.y = f2bf(v.y); o.z = f2bf(v.z); o.w = f2bf(v.w);
    ((ushort4*)abf)[i] = o;
}

// ---------------- convert + transpose W1 -> Wt[k][col][kk] bf16 ----------
__global__ __launch_bounds__(256) void w2bf_kernel(const float* __restrict__ W1,
                                                   unsigned short* __restrict__ Wt) {
    int k = blockIdx.x;
    for (int idx = threadIdx.x; idx < 64 * 256; idx += 256) {
        int c = idx >> 8;       // col 0..63
        int kk = idx & 255;     // k 0..255
        Wt[(size_t)k * 64 * 256 + c * 256 + kk] = f2bf(W1[(size_t)k * 256 * 64 + kk * 64 + c]);
    }
}

// ---------------- GEMM1 (MFMA): h = A @ W (M x 256 x 64), bf16 in/out ----
__global__ __launch_bounds__(256) void gemm1_mfma(
    const unsigned short* __restrict__ abf,  // [M,256] bf16
    const unsigned short* __restrict__ Wt,   // [64,256] bf16 (W^T)
    unsigned short* __restrict__ hbf,        // [M,64] bf16
    int M) {
    __shared__ __align__(16) unsigned short As[64][72];  // [row][k], +8 pad
    __shared__ __align__(16) unsigned short Bs[64][72];  // [col][k]
    int t = threadIdx.x;
    int row0 = blockIdx.x * 64;
    int wid = t >> 6, lane = t & 63;
    int qr = wid >> 1, qc = wid & 1;
    facc16 acc;
    for (int i = 0; i < 16; i++) acc[i] = 0.f;

    for (int kc = 0; kc < 256; kc += 64) {
        for (int i = 0; i < 2; i++) {
            int fid = t + i * 256;    // 0..511
            int r = fid >> 3;
            int o = (fid & 7) * 8;
            int row = row0 + r;
            uint4 v = make_uint4(0u, 0u, 0u, 0u);
            if (row < M) v = *(const uint4*)&abf[(size_t)row * 256 + kc + o];
            *(uint4*)&As[r][o] = v;
        }
        for (int i = 0; i < 2; i++) {
            int fid = t + i * 256;
            int c = fid >> 3;
            int o = (fid & 7) * 8;
            uint4 v = *(const uint4*)&Wt[(size_t)c * 256 + kc + o];
            *(uint4*)&Bs[c][o] = v;
        }
        __syncthreads();
        int arow = qr * 32 + (lane & 31);
        int bcol = qc * 32 + (lane & 31);
        int ko = (lane >> 5) * 8;
        for (int kk = 0; kk < 64; kk += 16) {
            bfrag8 a = *(const bfrag8*)&As[arow][kk + ko];
            bfrag8 b = *(const bfrag8*)&Bs[bcol][kk + ko];
            acc = __builtin_amdgcn_mfma_f32_32x32x16_bf16(a, b, acc, 0, 0, 0);
        }
        __syncthreads();
    }
    int col = qc * 32 + (lane & 31);
    for (int i = 0; i < 16; i++) {
        int rl = (i & 3) + 8 * (i >> 2) + 4 * (lane >> 5);
        int row = row0 + qr * 32 + rl;
        if (row < M) hbf[(size_t)row * 64 + col] = f2bf(acc[i]);
    }
}

// ---------------- GEMM1 fallback (fp32 VALU), bf16 out ----------------
__global__ __launch_bounds__(256) void gemm1_fp32(
    const float* __restrict__ A, const float* __restrict__ W,
    unsigned short* __restrict__ hbf, int M) {
    __shared__ __align__(16) float As[64][65];
    __shared__ __align__(16) float Ws[64][68];
    int t = threadIdx.x;
    int row0 = blockIdx.x * 64;
    int tr = t >> 4;
    int tc = t & 15;
    float acc[4][4] = {{0.f}};
    for (int kc = 0; kc < 256; kc += 64) {
        for (int i = 0; i < 4; i++) {
            int fid = t + i * 256;
            int r = fid >> 4;
            int c4 = (fid & 15) << 2;
            int row = row0 + r;
            float4 v = make_float4(0.f, 0.f, 0.f, 0.f);
            if (row < M) v = *(const float4*)&A[(size_t)row * 256 + kc + c4];
            As[r][c4] = v.x; As[r][c4 + 1] = v.y; As[r][c4 + 2] = v.z; As[r][c4 + 3] = v.w;
        }
        for (int i = 0; i < 4; i++) {
            int fid = t + i * 256;
            int r = fid >> 4;
            int c4 = (fid & 15) << 2;
            float4 v = *(const float4*)&W[(size_t)(kc + r) * 64 + c4];
            *(float4*)&Ws[r][c4] = v;
        }
        __syncthreads();
        for (int kk = 0; kk < 64; kk++) {
            float a0 = As[tr * 4 + 0][kk];
            float a1 = As[tr * 4 + 1][kk];
            float a2 = As[tr * 4 + 2][kk];
            float a3 = As[tr * 4 + 3][kk];
            float4 w = *(const float4*)&Ws[kk][tc * 4];
            acc[0][0] += a0 * w.x; acc[0][1] += a0 * w.y; acc[0][2] += a0 * w.z; acc[0][3] += a0 * w.w;
            acc[1][0] += a1 * w.x; acc[1][1] += a1 * w.y; acc[1][2] += a1 * w.z; acc[1][3] += a1 * w.w;
            acc[2][0] += a2 * w.x; acc[2][1] += a2 * w.y; acc[2][2] += a2 * w.z; acc[2][3] += a2 * w.w;
            acc[3][0] += a3 * w.x; acc[3][1] += a3 * w.y; acc[3][2] += a3 * w.z; acc[3][3] += a3 * w.w;
        }
        __syncthreads();
    }
    for (int i = 0; i < 4; i++) {
        int row = row0 + tr * 4 + i;
        if (row >= M) continue;
        ushort4 o;
        o.x = f2bf(acc[i][0]); o.y = f2bf(acc[i][1]);
        o.z = f2bf(acc[i][2]); o.w = f2bf(acc[i][3]);
        *(ushort4*)&hbf[(size_t)row * 64 + 4 * tc] = o;
    }
}

// ---------------- gather agg1: wave per node, 2 edges/iter (lane halves),
// bf16 h, fused relu + BN stats (hashed-slot global accumulate) ----------
__global__ __launch_bounds__(256) void gather1(const int* __restrict__ rowptr,
                                               const int* __restrict__ adj,
                                               const float* __restrict__ dis,
                                               const unsigned short* __restrict__ hbf,
                                               const float* __restrict__ b1,
                                               float* __restrict__ x,
                                               float* __restrict__ accum, int n) {
    __shared__ float ls[4][64];
    __shared__ float lq[4][64];
    ((float*)ls)[threadIdx.x] = 0.f;
    ((float*)lq)[threadIdx.x] = 0.f;
    __syncthreads();
    int w = threadIdx.x >> 6;
    int node = blockIdx.x * 4 + w;
    int lane = threadIdx.x & 63;
    int half = lane >> 5;
    int p = lane & 31;
    if (node < n) {
        int beg = rowptr[node], end = rowptr[node + 1];
        float ax = 0.f, ay = 0.f;
        int j = beg + half;
        for (; j + 2 < end; j += 4) {
            int s0 = adj[j], s1 = adj[j + 2];
            float d0 = dis[s0], d1 = dis[s1];
            unsigned u0 = *(const unsigned*)&hbf[(size_t)s0 * 64 + 2 * p];
            unsigned u1 = *(const unsigned*)&hbf[(size_t)s1 * 64 + 2 * p];
            ax += d0 * bf_lo(u0) + d1 * bf_lo(u1);
            ay += d0 * bf_hi(u0) + d1 * bf_hi(u1);
        }
        if (j < end) {
            int s0 = adj[j];
            float d0 = dis[s0];
            unsigned u0 = *(const unsigned*)&hbf[(size_t)s0 * 64 + 2 * p];
            ax += d0 * bf_lo(u0);
            ay += d0 * bf_hi(u0);
        }
        ax += __shfl_xor(ax, 32);
        ay += __shfl_xor(ay, 32);
        float dn = dis[node];
        float sc = 2.f * dn * dn;
        unsigned us = *(const unsigned*)&hbf[(size_t)node * 64 + 2 * p];
        float vx = dn * ax + sc * bf_lo(us) + b1[2 * p];
        float vy = dn * ay + sc * bf_hi(us) + b1[2 * p + 1];
        vx = fmaxf(vx, 0.f);
        vy = fmaxf(vy, 0.f);
        if (half == 0) {
            *(float2*)&x[(size_t)node * 64 + 2 * p] = make_float2(vx, vy);
            ls[w][2 * p] = vx;
            ls[w][2 * p + 1] = vy;
            lq[w][2 * p] = vx * vx;
            lq[w][2 * p + 1] = vy * vy;
        }
    }
    __syncthreads();
    if (threadIdx.x < 64) {
        int c = threadIdx.x;
        float S = ls[0][c] + ls[1][c] + ls[2][c] + ls[3][c];
        float Q = lq[0][c] + lq[1][c] + lq[2][c] + lq[3][c];
        float* slot = accum + (size_t)(blockIdx.x & (SLOTS - 1)) * 128;
        unsafeAtomicAdd(&slot[c], S);
        unsafeAtomicAdd(&slot[64 + c], Q);
    }
}

// ---------------- BN apply + GEMM2 (64 -> 2), stats finalized inline ------
__global__ __launch_bounds__(256) void bn_gemm2(const float* __restrict__ x,
                                                const float* __restrict__ accum,
                                                const float* __restrict__ g,
                                                const float* __restrict__ bt,
                                                const float* __restrict__ W2,
                                                float* __restrict__ h2, int M) {
    __shared__ float a_s[64], b_s[64];
    int t = threadIdx.x;
    if (t < 64) {
        float S = 0.f, Q = 0.f;
        for (int s = 0; s < SLOTS; s++) {
            S += accum[(size_t)s * 128 + t];
            Q += accum[(size_t)s * 128 + 64 + t];
        }
        float mu = S / (float)M;
        float var = Q / (float)M - mu * mu;
        float istdg = rsqrtf(var + EPSV) * g[t];
        a_s[t] = istdg;
        b_s[t] = bt[t] - mu * istdg;
    }
    __syncthreads();
    int w = t >> 6;
    int c = t & 63;
    float a = a_s[c], b = b_s[c];
    float w20 = W2[c * 2], w21 = W2[c * 2 + 1];
    for (int node = blockIdx.x * 4 + w; node < M; node += gridDim.x * 4) {
        float v = x[(size_t)node * 64 + c] * a + b;
        float p0 = v * w20;
        float p1 = v * w21;
        for (int off = 32; off; off >>= 1) {
            p0 += __shfl_down(p0, off);
            p1 += __shfl_down(p1, off);
        }
        if (c == 0) *(float2*)&h2[(size_t)node * 2] = make_float2(p0, p1);
    }
}

// ---------------- gather agg2: thread per node, batched over experts ------
__global__ __launch_bounds__(256) void gather2_all(const int* __restrict__ rowptr,
                                                   const int* __restrict__ adj,
                                                   const float* __restrict__ dis,
                                                   const float* __restrict__ h2all,
                                                   const float* __restrict__ b2,
                                                   float* __restrict__ agg2,
                                                   int n, int E) {
    int k = blockIdx.y;
    const int* rp = rowptr + (size_t)k * (n + 1);
    const int* aj = adj + (size_t)k * E;
    const float* dk = dis + (size_t)k * n;
    const float* h2 = h2all + (size_t)k * n * 2;
    float* ag = agg2 + (size_t)k * n * 2;
    int node = blockIdx.x * 256 + threadIdx.x;
    if (node >= n) return;
    int beg = rp[node], end = rp[node + 1];
    float a0 = 0.f, a1 = 0.f;
    int j = beg;
    for (; j + 2 <= end; j += 2) {
        int s0 = aj[j], s1 = aj[j + 1];
        float d0 = dk[s0], d1 = dk[s1];
        float2 v0 = *(const float2*)&h2[(size_t)s0 * 2];
        float2 v1 = *(const float2*)&h2[(size_t)s1 * 2];
        a0 += d0 * v0.x + d1 * v1.x;
        a1 += d0 * v0.y + d1 * v1.y;
    }
    if (j < end) {
        int s0 = aj[j];
        float d0 = dk[s0];
        float2 v0 = *(const float2*)&h2[(size_t)s0 * 2];
        a0 += d0 * v0.x;
        a1 += d0 * v0.y;
    }
    float dn = dk[node];
    float sc = 2.f * dn * dn;
    float2 hv = *(const float2*)&h2[(size_t)node * 2];
    float2 o;
    o.x = dn * a0 + sc * hv.x + b2[k * 2];
    o.y = dn * a1 + sc * hv.y + b2[k * 2 + 1];
    *(float2*)&ag[(size_t)node * 2] = o;
}

// ---------------- gating + mixture output ----------------
__global__ __launch_bounds__(256) void final_kernel(const float* __restrict__ moe,
                                                    const float* __restrict__ Wg,
                                                    const float* __restrict__ bg,
                                                    const float* __restrict__ agg2,  // [K][N][2]
                                                    float* __restrict__ out, int M) {
    int n = (int)((blockIdx.x * (size_t)blockDim.x + threadIdx.x) >> 6);
    int lane = threadIdx.x & 63;
    if (n >= M) return;
    float4 mf = *(const float4*)&moe[(size_t)n * 256 + lane * 4];
    const float* wr = &Wg[lane * 16];
    float a0 = mf.x * wr[0] + mf.y * wr[4] + mf.z * wr[8] + mf.w * wr[12];
    float a1 = mf.x * wr[1] + mf.y * wr[5] + mf.z * wr[9] + mf.w * wr[13];
    float a2 = mf.x * wr[2] + mf.y * wr[6] + mf.z * wr[10] + mf.w * wr[14];
    float a3 = mf.x * wr[3] + mf.y * wr[7] + mf.z * wr[11] + mf.w * wr[15];
    for (int mask = 1; mask < 64; mask <<= 1) {
        a0 += __shfl_xor(a0, mask);
        a1 += __shfl_xor(a1, mask);
        a2 += __shfl_xor(a2, mask);
        a3 += __shfl_xor(a3, mask);
    }
    if (lane == 0) {
        float gl[4] = {a0 + bg[0], a1 + bg[1], a2 + bg[2], a3 + bg[3]};
        float m = fmaxf(fmaxf(gl[0], gl[1]), fmaxf(gl[2], gl[3]));
        float w[4];
        float wsum = 0.f;
        for (int kk = 0; kk < 4; kk++) { w[kk] = expf(gl[kk] - m); wsum += w[kk]; }
        float o0 = 0.f, o1 = 0.f, q0 = 0.f, q1 = 0.f;
        for (int kk = 0; kk < 4; kk++) {
            float l0 = agg2[((size_t)kk * M + n) * 2];
            float l1 = agg2[((size_t)kk * M + n) * 2 + 1];
            float mm = fmaxf(l0, l1);
            float lse = mm + logf(expf(l0 - mm) + expf(l1 - mm));
            float lp0 = l0 - lse, lp1 = l1 - lse;
            float wk = w[kk] / wsum;
            o0 += wk * lp0; o1 += wk * lp1;
            q0 += wk * expf(lp0); q1 += wk * expf(lp1);
        }
        out[(size_t)n * 2] = o0;
        out[(size_t)n * 2 + 1] = o1;
        out[(size_t)2 * M + n * 2] = q0;
        out[(size_t)2 * M + n * 2 + 1] = q1;
    }
}

extern "C" void kernel_launch(void* const* d_in, const int* in_sizes, int n_in,
                              void* d_out, int out_size, void* d_ws, size_t ws_size,
                              hipStream_t stream) {
    const float* flatten = (const float*)d_in[0];
    const float* moe     = (const float*)d_in[1];
    const int*   edge    = (const int*)d_in[2];   // [K][2][E]
    const float* W1      = (const float*)d_in[3]; // [K][256][64]
    const float* b1      = (const float*)d_in[4]; // [K][64]
    const float* gamma   = (const float*)d_in[5];
    const float* beta    = (const float*)d_in[6];
    const float* W2      = (const float*)d_in[7]; // [K][64][2]
    const float* b2      = (const float*)d_in[8]; // [K][2]
    const float* Wg      = (const float*)d_in[9]; // [256][4]
    const float* bg      = (const float*)d_in[10];
    float* out = (float*)d_out;

    const int N = NN, E = EE, K = KEXP;

    char* ws = (char*)d_ws;
    size_t off = 0;
    auto alloc = [&](size_t bytes) -> void* {
        void* p = (void*)(ws + off);
        off += (bytes + 255) & ~(size_t)255;
        return p;
    };
    int*   rowptr    = (int*)alloc((size_t)K * (N + 1) * 4);
    float* dis       = (float*)alloc((size_t)K * N * 4);
    int*   blockhist = (int*)alloc((size_t)K * PG * NBUCK * 4);
    int*   bbase     = (int*)alloc((size_t)K * (NBUCK + 1) * 4);
    int*   adj       = (int*)alloc((size_t)K * E * 4);
    unsigned short* hbf = (unsigned short*)alloc((size_t)N * 64 * 2);
    float* x         = (float*)alloc((size_t)N * 64 * 4);
    float* h2all     = (float*)alloc((size_t)K * N * 2 * 4);
    float* agg2      = (float*)alloc((size_t)K * N * 2 * 4);
    float* accum     = (float*)alloc((size_t)K * SLOTS * 128 * 4);
    size_t base_need = off;
    unsigned short* abf = (unsigned short*)alloc((size_t)N * 256 * 2);
    unsigned short* Wt  = (unsigned short*)alloc((size_t)K * 64 * 256 * 2);
    size_t mfma_need = off;
    (void)in_sizes; (void)n_in; (void)out_size; (void)base_need;
    bool use_mfma = (ws_size >= mfma_need);

    // bstream (K*E*4 = 25.6 MB) aliases hbf+x (12.8+25.6 MB contiguous):
    // only used in the build phase, before gemm1/gather1 write hbf/x.
    unsigned* bstream = (unsigned*)hbf;

    // ---- batched CSR build: atomic-free 3-pass bucket radix sort ----
    hipMemsetAsync(accum, 0, (size_t)K * SLOTS * 128 * 4, stream);
    hist_pass<<<dim3(PG, K), 256, 0, stream>>>(edge, blockhist, E);
    scan_pass<<<K, 256, 0, stream>>>(blockhist, bbase, rowptr, N, E);
    partition_pass<<<dim3(PG, K), 256, 0, stream>>>(edge, blockhist, bbase, bstream, E);
    bucket_build<<<dim3(NBUCK, K), 256, 0, stream>>>(bbase, bstream, rowptr, dis, adj, N, E);

    if (use_mfma) {
        a2bf_kernel<<<(N * 256 / 4 + 255) / 256, 256, 0, stream>>>(flatten, abf, N * 256 / 4);
        w2bf_kernel<<<K, 256, 0, stream>>>(W1, Wt);
    }

    // ---- per-expert pipeline ----
    for (int k = 0; k < K; k++) {
        const int* rp = rowptr + (size_t)k * (N + 1);
        const int* aj = adj + (size_t)k * E;
        const float* dk = dis + (size_t)k * N;
        float* ak = accum + (size_t)k * SLOTS * 128;
        if (use_mfma) {
            gemm1_mfma<<<(N + 63) / 64, 256, 0, stream>>>(
                abf, Wt + (size_t)k * 64 * 256, hbf, N);
        } else {
            gemm1_fp32<<<(N + 63) / 64, 256, 0, stream>>>(
                flatten, W1 + (size_t)k * 256 * 64, hbf, N);
        }
        gather1<<<(N + 3) / 4, 256, 0, stream>>>(
            rp, aj, dk, hbf, b1 + (size_t)k * 64, x, ak, N);
        bn_gemm2<<<1024, 256, 0, stream>>>(
            x, ak, gamma + (size_t)k * 64, beta + (size_t)k * 64,
            W2 + (size_t)k * 128, h2all + (size_t)k * N * 2, N);
    }
    gather2_all<<<dim3((N + 255) / 256, K), 256, 0, stream>>>(
        rowptr, adj, dis, h2all, b2, agg2, N, E);
    final_kernel<<<(int)(((size_t)N * 64 + 255) / 256), 256, 0, stream>>>(
        moe, Wg, bg, agg2, out, N);
}